// Round 9
// baseline (3292.950 us; speedup 1.0000x reference)
//
#include <hip/hip_runtime.h>
#include <hip/hip_bf16.h>
#include <cstdint>
#include <cstddef>

#define Dm 1024
#define Sm 512
#define Bm 2
#define Nm 4096
#define Lm 4
#define Vm 32000

typedef __attribute__((ext_vector_type(8))) short short8;
typedef __attribute__((ext_vector_type(4))) float floatx4;

__device__ __forceinline__ unsigned short f2b(float f){
  union { float f; unsigned u; } v; v.f = f;
  unsigned r = (v.u + 0x7fffu + ((v.u >> 16) & 1u)) >> 16;
  return (unsigned short)r;
}
__device__ __forceinline__ float b2f(unsigned short h){
  union { unsigned u; float f; } v; v.u = ((unsigned)h) << 16;
  return v.f;
}

// async global->LDS, 16B per lane; LDS dest = wave-uniform base + lane*16
__device__ __forceinline__ void gload16(const unsigned short* g, unsigned short* l){
  __builtin_amdgcn_global_load_lds(
      (const __attribute__((address_space(1))) void*)g,
      (__attribute__((address_space(3))) void*)l, 16, 0, 0);
}

// ---------------- fused abs-sum for all 10 ternary weights (deterministic f64) ----------------
__global__ __launch_bounds__(256) void absum_all_kernel(
    const float* __restrict__ emb, const float* __restrict__ syn_w,
    const float* __restrict__ out_w, const float* __restrict__ head_w,
    double* __restrict__ partial)
{
  int wid = blockIdx.x >> 7;        // 0..9
  int blk = blockIdx.x & 127;
  const float* base; long n4;
  if (wid == 0){ base = emb; n4 = (long)Vm * Dm / 4; }
  else if (wid <= 4){ base = syn_w + (size_t)(wid - 1) * Nm * Dm; n4 = (long)Nm * Dm / 4; }
  else if (wid <= 8){ base = out_w + (size_t)(wid - 5) * Dm * Nm; n4 = (long)Nm * Dm / 4; }
  else { base = head_w; n4 = (long)Vm * Dm / 4; }

  long i = (long)blk * 256 + threadIdx.x;
  const long stride = 128L * 256;
  double s = 0.0;
  for (; i < n4; i += stride){
    float4 v = ((const float4*)base)[i];
    s += (double)fabsf(v.x) + (double)fabsf(v.y) + (double)fabsf(v.z) + (double)fabsf(v.w);
  }
  #pragma unroll
  for (int off = 32; off; off >>= 1) s += __shfl_down(s, off, 64);
  __shared__ double wsum[4];
  int lane = threadIdx.x & 63, wv = threadIdx.x >> 6;
  if (lane == 0) wsum[wv] = s;
  __syncthreads();
  if (threadIdx.x == 0) partial[wid * 128 + blk] = wsum[0] + wsum[1] + wsum[2] + wsum[3];
}

// one block per scale: fixed-order f64 reduce of 128 partials -> mean (f32)
__global__ __launch_bounds__(128) void scale_kernel(const double* __restrict__ partials,
                                                    float* __restrict__ scales){
  int b = blockIdx.x;
  int tid = threadIdx.x;
  __shared__ double red[128];
  red[tid] = partials[b * 128 + tid];
  __syncthreads();
  for (int off = 64; off; off >>= 1){
    if (tid < off) red[tid] += red[tid + off];
    __syncthreads();
  }
  if (tid == 0){
    double cnt = (b == 0 || b == 9) ? (double)Vm * (double)Dm : (double)Nm * (double)Dm;
    scales[b] = (float)(red[0] / cnt);
  }
}

// ---------------- ternarize weights -> bf16 (values in {-1,0,1}, exact) ----------------
__global__ __launch_bounds__(256) void tern_kernel(const float* __restrict__ w,
                                                   const float* __restrict__ smean,
                                                   unsigned short* __restrict__ out, long n4){
  float s = smean[0] + 1e-8f;
  long i = (long)blockIdx.x * blockDim.x + threadIdx.x;
  long stride = (long)gridDim.x * blockDim.x;
  for (; i < n4; i += stride){
    float4 v = ((const float4*)w)[i];
    ushort4 o;
    o.x = f2b(rintf(fminf(fmaxf(v.x / s, -1.f), 1.f)));
    o.y = f2b(rintf(fminf(fmaxf(v.y / s, -1.f), 1.f)));
    o.z = f2b(rintf(fminf(fmaxf(v.z / s, -1.f), 1.f)));
    o.w = f2b(rintf(fminf(fmaxf(v.w / s, -1.f), 1.f)));
    ((ushort4*)out)[i] = o;
  }
}

// ---------------- split f32 -> bf16 hi + lo planes ----------------
__global__ __launch_bounds__(256) void split_kernel(const float* __restrict__ w,
                                                    unsigned short* __restrict__ hi,
                                                    unsigned short* __restrict__ lo, long n4){
  long i = (long)blockIdx.x * blockDim.x + threadIdx.x;
  long stride = (long)gridDim.x * blockDim.x;
  for (; i < n4; i += stride){
    float4 v = ((const float4*)w)[i];
    float f[4] = {v.x, v.y, v.z, v.w};
    ushort4 h4, l4;
    unsigned short* hp = (unsigned short*)&h4;
    unsigned short* lp = (unsigned short*)&l4;
    #pragma unroll
    for (int e = 0; e < 4; e++){
      unsigned short h = f2b(f[e]);
      hp[e] = h;
      lp[e] = f2b(f[e] - b2f(h));
    }
    ((ushort4*)hi)[i] = h4;
    ((ushort4*)lo)[i] = l4;
  }
}

// ---------------- ternary embedding + positional -> bf16 hi/lo planes ----------------
__global__ __launch_bounds__(256) void embed_kernel(
    const int* __restrict__ ids, const float* __restrict__ emb,
    const float* __restrict__ pos, const float* __restrict__ smean,
    unsigned short* __restrict__ xhi, unsigned short* __restrict__ xlo)
{
  int row = blockIdx.x;            // b*512 + s
  int sp  = row & (Sm - 1);
  int id  = ids[row];
  float s = smean[0] + 1e-8f;
  int d = threadIdx.x * 4;
  float4 wv = *(const float4*)(emb + (size_t)id * Dm + d);
  float4 pv = *(const float4*)(pos + (size_t)sp * Dm + d);
  float y[4];
  y[0] = s * rintf(fminf(fmaxf(wv.x / s, -1.f), 1.f)) + pv.x;
  y[1] = s * rintf(fminf(fmaxf(wv.y / s, -1.f), 1.f)) + pv.y;
  y[2] = s * rintf(fminf(fmaxf(wv.z / s, -1.f), 1.f)) + pv.z;
  y[3] = s * rintf(fminf(fmaxf(wv.w / s, -1.f), 1.f)) + pv.w;
  ushort4 h4, l4;
  unsigned short* hp = (unsigned short*)&h4;
  unsigned short* lp = (unsigned short*)&l4;
  #pragma unroll
  for (int e = 0; e < 4; e++){
    unsigned short h = f2b(y[e]);
    hp[e] = h;
    lp[e] = f2b(y[e] - b2f(h));
  }
  size_t base = (size_t)row * Dm + d;
  *(ushort4*)(xhi + base) = h4;
  *(ushort4*)(xlo + base) = l4;
}

// ---------------- reg-staged GEMM (BT=64/128), pre-split bf16 planes ----------------
// Used for gi/syn/out GEMMs (grids 512-1024 blocks, 2-4/CU: multi-block overlap
// regime where reg-staging beats the barrier-drain lds kernel — R6 lesson).
// split-K capped at 2 — two-addend f32 atomicAdd commutes -> deterministic.
template<bool WSPLIT, bool WF32, int BT>
__global__ __launch_bounds__(256) void gemm_kernel(
    const unsigned short* __restrict__ Ahi, const unsigned short* __restrict__ Alo,
    const void* __restrict__ Wsrc, const unsigned short* __restrict__ Wlo,
    const float* __restrict__ bias, const float* __restrict__ smean,
    int relu, float* __restrict__ outf,
    unsigned short* __restrict__ outhi, unsigned short* __restrict__ outlo,
    int M, int N, int K)
{
  constexpr int WT = BT / 2;
  constexpr int FT = WT / 16;
  constexpr int RPT = 256 / BT;
  constexpr int CPT = 32 / RPT;
  constexpr int NU  = CPT / 8;

  __shared__ unsigned short As[2][BT][40];
  __shared__ unsigned short Bs[WSPLIT ? 2 : 1][BT][40];
  int tid = threadIdx.x;
  int wave = tid >> 6, lane = tid & 63;
  int wm = wave >> 1, wn = wave & 1;
  int bm = blockIdx.y, bn = blockIdx.x;

  bool tern = (smean != nullptr);
  float s = 1.f;
  if (tern) s = smean[0] + 1e-8f;

  int arow = tid / RPT, sub = tid % RPT;
  int col0 = sub * CPT;
  const unsigned short* Agh = Ahi + (size_t)(bm * BT + arow) * K + col0;
  const unsigned short* Agl = Alo + (size_t)(bm * BT + arow) * K + col0;
  const float* Wgf = nullptr;
  const unsigned short* Wgh = nullptr;
  const unsigned short* Wgl = nullptr;
  if (WF32) Wgf = (const float*)Wsrc + (size_t)(bn * BT + arow) * K + col0;
  else {
    Wgh = (const unsigned short*)Wsrc + (size_t)(bn * BT + arow) * K + col0;
    if (WSPLIT) Wgl = Wlo + (size_t)(bn * BT + arow) * K + col0;
  }

  floatx4 acc[FT][FT];
  #pragma unroll
  for (int i = 0; i < FT; i++)
    #pragma unroll
    for (int j = 0; j < FT; j++)
      acc[i][j] = (floatx4){0.f, 0.f, 0.f, 0.f};

  int kpb = K / (int)gridDim.z;
  int k_beg = blockIdx.z * kpb;

  for (int k0 = k_beg; k0 < k_beg + kpb; k0 += 32){
    __syncthreads();
    #pragma unroll
    for (int u = 0; u < NU; u++){
      *(uint4*)&As[0][arow][col0 + u * 8] = *(const uint4*)(Agh + k0 + u * 8);
      *(uint4*)&As[1][arow][col0 + u * 8] = *(const uint4*)(Agl + k0 + u * 8);
    }
    if (WF32){
      unsigned short tmp[CPT];
      #pragma unroll
      for (int q = 0; q < CPT / 4; q++){
        float4 wv = *(const float4*)(Wgf + k0 + q * 4);
        float f[4] = {wv.x, wv.y, wv.z, wv.w};
        #pragma unroll
        for (int e = 0; e < 4; e++){
          float w = f[e];
          if (tern) w = rintf(fminf(fmaxf(w / s, -1.f), 1.f));
          tmp[q * 4 + e] = f2b(w);
        }
      }
      #pragma unroll
      for (int u = 0; u < NU; u++)
        *(uint4*)&Bs[0][arow][col0 + u * 8] = *(uint4*)&tmp[u * 8];
    } else {
      #pragma unroll
      for (int u = 0; u < NU; u++){
        *(uint4*)&Bs[0][arow][col0 + u * 8] = *(const uint4*)(Wgh + k0 + u * 8);
        if (WSPLIT)
          *(uint4*)&Bs[1][arow][col0 + u * 8] = *(const uint4*)(Wgl + k0 + u * 8);
      }
    }
    __syncthreads();

    int kq = lane >> 4, mr = lane & 15;
    short8 afh[FT], afl[FT], bfh[FT];
    #pragma unroll
    for (int i = 0; i < FT; i++){
      afh[i] = *(const short8*)&As[0][wm*WT + i*16 + mr][kq*8];
      afl[i] = *(const short8*)&As[1][wm*WT + i*16 + mr][kq*8];
    }
    #pragma unroll
    for (int j = 0; j < FT; j++) bfh[j] = *(const short8*)&Bs[0][wn*WT + j*16 + mr][kq*8];
    #pragma unroll
    for (int i = 0; i < FT; i++)
      #pragma unroll
      for (int j = 0; j < FT; j++){
        acc[i][j] = __builtin_amdgcn_mfma_f32_16x16x32_bf16(afh[i], bfh[j], acc[i][j], 0, 0, 0);
        acc[i][j] = __builtin_amdgcn_mfma_f32_16x16x32_bf16(afl[i], bfh[j], acc[i][j], 0, 0, 0);
      }
    if (WSPLIT){
      short8 bfl[FT];
      #pragma unroll
      for (int j = 0; j < FT; j++) bfl[j] = *(const short8*)&Bs[1][wn*WT + j*16 + mr][kq*8];
      #pragma unroll
      for (int i = 0; i < FT; i++)
        #pragma unroll
        for (int j = 0; j < FT; j++)
          acc[i][j] = __builtin_amdgcn_mfma_f32_16x16x32_bf16(afh[i], bfl[j], acc[i][j], 0, 0, 0);
    }
  }

  bool split = (gridDim.z > 1);
  bool addb = (blockIdx.z == 0);
  int cr = lane >> 4, cc = lane & 15;
  #pragma unroll
  for (int j = 0; j < FT; j++){
    int col = bn * BT + wn * WT + j * 16 + cc;
    float bv = (bias && addb) ? bias[col] : 0.f;
    #pragma unroll
    for (int i = 0; i < FT; i++){
      #pragma unroll
      for (int r = 0; r < 4; r++){
        int row = bm * BT + wm * WT + i * 16 + cr * 4 + r;
        float v = acc[i][j][r] * s + bv;
        if (relu) v = fmaxf(v, 0.f);
        size_t idx = (size_t)row * N + col;
        if (outf){
          if (split) atomicAdd(outf + idx, v);
          else outf[idx] = v;
        }
        if (outhi){
          unsigned short h = f2b(v);
          outhi[idx] = h;
          outlo[idx] = f2b(v - b2f(h));
        }
      }
    }
  }
}

// ---------------- lds-staged GEMM: global_load_lds, 128x128 tile (HEAD ONLY) ----------------
// Profitable only when grid >> 256 blocks (head = 2000 blocks, 7.8/CU).
__global__ __launch_bounds__(256) void gemm_lds_kernel(
    const unsigned short* __restrict__ Ahi, const unsigned short* __restrict__ Alo,
    const unsigned short* __restrict__ Whi,
    const float* __restrict__ bias, const float* __restrict__ smean,
    int relu, float* __restrict__ outf, int M, int N, int K)
{
  __shared__ __align__(16) unsigned short lds[3 * 4096];   // planes of [128][32] bf16
  int tid = threadIdx.x;
  int wave = tid >> 6, lane = tid & 63;
  int wm = wave >> 1, wn = wave & 1;
  int bm = blockIdx.y, bn = blockIdx.x;

  float s = 1.f;
  if (smean) s = smean[0] + 1e-8f;

  int r0 = wave * 32 + (lane >> 2);
  int r1 = r0 + 16;
  int s0 = (lane & 3) ^ ((r0 >> 1) & 3);
  int s1 = (lane & 3) ^ ((r1 >> 1) & 3);
  const unsigned short* ga0 = Ahi + (size_t)(bm * 128 + r0) * K + s0 * 8;
  const unsigned short* ga1 = Ahi + (size_t)(bm * 128 + r1) * K + s1 * 8;
  const unsigned short* gl0 = Alo + (size_t)(bm * 128 + r0) * K + s0 * 8;
  const unsigned short* gl1 = Alo + (size_t)(bm * 128 + r1) * K + s1 * 8;
  const unsigned short* gw0 = Whi + (size_t)(bn * 128 + r0) * K + s0 * 8;
  const unsigned short* gw1 = Whi + (size_t)(bn * 128 + r1) * K + s1 * 8;
  unsigned short* la = &lds[wave * 1024];

  floatx4 acc[4][4];
  #pragma unroll
  for (int i = 0; i < 4; i++)
    #pragma unroll
    for (int j = 0; j < 4; j++)
      acc[i][j] = (floatx4){0.f, 0.f, 0.f, 0.f};

  for (int k0 = 0; k0 < K; k0 += 32){
    __syncthreads();
    gload16(ga0 + k0, la);
    gload16(ga1 + k0, la + 512);
    gload16(gl0 + k0, la + 4096);
    gload16(gl1 + k0, la + 4096 + 512);
    gload16(gw0 + k0, la + 8192);
    gload16(gw1 + k0, la + 8192 + 512);
    __syncthreads();

    int kq = lane >> 4, mr = lane & 15;
    short8 afh[4], afl[4], bfh[4];
    #pragma unroll
    for (int i = 0; i < 4; i++){
      int r = wm * 64 + i * 16 + mr;
      int off = r * 32 + ((kq ^ ((r >> 1) & 3)) << 3);
      afh[i] = *(const short8*)&lds[off];
      afl[i] = *(const short8*)&lds[4096 + off];
    }
    #pragma unroll
    for (int j = 0; j < 4; j++){
      int r = wn * 64 + j * 16 + mr;
      int off = r * 32 + ((kq ^ ((r >> 1) & 3)) << 3);
      bfh[j] = *(const short8*)&lds[8192 + off];
    }
    #pragma unroll
    for (int i = 0; i < 4; i++)
      #pragma unroll
      for (int j = 0; j < 4; j++){
        acc[i][j] = __builtin_amdgcn_mfma_f32_16x16x32_bf16(afh[i], bfh[j], acc[i][j], 0, 0, 0);
        acc[i][j] = __builtin_amdgcn_mfma_f32_16x16x32_bf16(afl[i], bfh[j], acc[i][j], 0, 0, 0);
      }
  }

  int cr = lane >> 4, cc = lane & 15;
  #pragma unroll
  for (int j = 0; j < 4; j++){
    int col = bn * 128 + wn * 64 + j * 16 + cc;
    float bv = bias ? bias[col] : 0.f;
    #pragma unroll
    for (int i = 0; i < 4; i++){
      #pragma unroll
      for (int r = 0; r < 4; r++){
        int row = bm * 128 + wm * 64 + i * 16 + cr * 4 + r;
        float v = acc[i][j][r] * s + bv;
        if (relu) v = fmaxf(v, 0.f);
        outf[(size_t)row * N + col] = v;
      }
    }
  }
}

// ---------------- persistent GRU over 512 steps (fence-free tagged exchange) ----------------
// 64 WGs x 1024 threads. Sync protocol = R3 config (all-thread 2-word poll,
// s_sleep(1) backoff, relaxed tagged u64).
// Dot decomposition (4x LDS-reuse): wave dl (16 waves) owns dim d0+dl, ALL 3
// gates; lane c owns h-chunk [c*16, c*16+16). Each loaded float4 feeds 3 FMAs
// -> LDS read traffic 384KB -> 128KB per WG/step. Intra-wave shfl reduction
// puts gate sums in lane 0 -> pointwise + store there; 2nd barrier eliminated.
// SAFETY (overwrite): producer stores tag t+3 only after its WG's barrier(t+2),
// whose WG-wide poll(t+2) requires tags t+2 from ALL 64 WGs, each of which
// stored only after completing poll(t+1) (reading tag t+1) -> no slot is
// overwritten before all readers finish. LDS parity reuse barrier-protected.
__global__ __launch_bounds__(1024) void gru_kernel(
    const float* __restrict__ gi, const float* __restrict__ whh, const float* __restrict__ bhh,
    unsigned long long* __restrict__ hbuf, float* __restrict__ hs,
    unsigned short* __restrict__ xhi, unsigned short* __restrict__ xlo)
{
  __shared__ float lds_h[2][2][1024];     // [parity][batch][swizzled dim]
  int w = blockIdx.x, tid = threadIdx.x;
  int d0 = w * 16;
  int dl = tid >> 6;                      // wave = local dim 0..15
  int c  = tid & 63;                      // chunk of 16
  int d  = d0 + dl;

  // weights: 3 gate rows of dim d, cols [c*16, c*16+16)
  float wreg[3][16];
  #pragma unroll
  for (int g = 0; g < 3; g++){
    const float* src = whh + (size_t)(g * Dm + d) * Dm + c * 16;
    #pragma unroll
    for (int q = 0; q < 4; q++){
      float4 v = *(const float4*)(src + q * 4);
      wreg[g][q*4+0] = v.x; wreg[g][q*4+1] = v.y;
      wreg[g][q*4+2] = v.z; wreg[g][q*4+3] = v.w;
    }
  }
  float bh[3];
  #pragma unroll
  for (int g = 0; g < 3; g++) bh[g] = bhh[g * Dm + d];

  float hprev0 = 0.f, hprev1 = 0.f;       // lane 0 state

  for (int t = 0; t < Sm; t++){
    // --- gi prefetch (lane 0 of each wave; overlaps with poll) ---
    float ir0=0.f, iz0=0.f, in0=0.f, ir1=0.f, iz1=0.f, in1=0.f;
    if (c == 0){
      const float* g0 = gi + (size_t)t * (3 * Dm);
      const float* g1 = gi + ((size_t)Sm + t) * (3 * Dm);
      ir0 = g0[d]; iz0 = g0[Dm + d]; in0 = g0[2*Dm + d];
      ir1 = g1[d]; iz1 = g1[Dm + d]; in1 = g1[2*Dm + d];
    }
    // --- poll: 2 tagged words/thread, swizzled LDS write on arrival ---
    {
      const unsigned long long* src = hbuf + (size_t)(t & 1) * 2048 + tid * 2;
      float* ldst = &lds_h[t & 1][0][0];
      unsigned got = 0;
      int spins = 0;
      while (got != 3u){
        #pragma unroll
        for (int q = 0; q < 2; q++){
          if (!(got & (1u << q))){
            unsigned long long wd = __hip_atomic_load(src + q, __ATOMIC_RELAXED,
                                                      __HIP_MEMORY_SCOPE_AGENT);
            if ((unsigned)(wd >> 32) == (unsigned)t){
              union { unsigned u; float f; } cv; cv.u = (unsigned)wd;
              int wi = tid * 2 + q;
              int b = wi >> 10, dv = wi & 1023;
              ldst[b * 1024 + ((dv >> 2) & 3) * 256 + (dv >> 4) * 4 + (dv & 3)] = cv.f;
              got |= 1u << q;
            }
          }
        }
        if (got != 3u){
          if (++spins > (1 << 18)) break;   // safety: degrade fast, don't hang
          __builtin_amdgcn_s_sleep(1);
        }
      }
    }
    __syncthreads();
    // --- dot: 3 gates x 2 batches, 16 h-values per lane, 4x reuse ---
    float acc[3][2] = {{0.f,0.f},{0.f,0.f},{0.f,0.f}};
    const float* hp = &lds_h[t & 1][0][0];
    #pragma unroll
    for (int b = 0; b < 2; b++){
      #pragma unroll
      for (int q = 0; q < 4; q++){
        float4 hv = *(const float4*)&hp[b * 1024 + q * 256 + c * 4];
        #pragma unroll
        for (int g = 0; g < 3; g++){
          acc[g][b] += wreg[g][q*4+0] * hv.x;
          acc[g][b] += wreg[g][q*4+1] * hv.y;
          acc[g][b] += wreg[g][q*4+2] * hv.z;
          acc[g][b] += wreg[g][q*4+3] * hv.w;
        }
      }
    }
    #pragma unroll
    for (int off = 32; off; off >>= 1){
      #pragma unroll
      for (int g = 0; g < 3; g++){
        acc[g][0] += __shfl_xor(acc[g][0], off, 64);
        acc[g][1] += __shfl_xor(acc[g][1], off, 64);
      }
    }
    // --- pointwise + tagged store (lane 0 of each wave; no 2nd barrier) ---
    if (c == 0){
      float gr0 = acc[0][0] + bh[0], gz0 = acc[1][0] + bh[1], gn0 = acc[2][0] + bh[2];
      float gr1 = acc[0][1] + bh[0], gz1 = acc[1][1] + bh[1], gn1 = acc[2][1] + bh[2];
      float rr0 = 1.f / (1.f + expf(-(ir0 + gr0)));
      float zz0 = 1.f / (1.f + expf(-(iz0 + gz0)));
      float nn0 = tanhf(in0 + rr0 * gn0);
      float h0 = (1.f - zz0) * nn0 + zz0 * hprev0;
      float rr1 = 1.f / (1.f + expf(-(ir1 + gr1)));
      float zz1 = 1.f / (1.f + expf(-(iz1 + gz1)));
      float nn1 = tanhf(in1 + rr1 * gn1);
      float h1 = (1.f - zz1) * nn1 + zz1 * hprev1;
      hprev0 = h0; hprev1 = h1;
      unsigned long long* dst = hbuf + (size_t)((t + 1) & 1) * 2048;
      union { float f; unsigned u; } cv0, cv1; cv0.f = h0; cv1.f = h1;
      unsigned long long tag = (unsigned long long)(unsigned)(t + 1) << 32;
      __hip_atomic_store(dst + d,        tag | cv0.u, __ATOMIC_RELAXED, __HIP_MEMORY_SCOPE_AGENT);
      __hip_atomic_store(dst + 1024 + d, tag | cv1.u, __ATOMIC_RELAXED, __HIP_MEMORY_SCOPE_AGENT);
      size_t oi0 = (size_t)t * Dm + d;
      size_t oi1 = ((size_t)Sm + t) * Dm + d;
      hs[oi0] = h0; hs[oi1] = h1;
      unsigned short hh0 = f2b(h0), hh1 = f2b(h1);
      xhi[oi0] = hh0; xlo[oi0] = f2b(h0 - b2f(hh0));
      xhi[oi1] = hh1; xlo[oi1] = f2b(h1 - b2f(hh1));
    }
  }
}

// ---------------- layernorm (+optional residual add) -> f32 and/or bf16 planes ----------------
__global__ __launch_bounds__(256) void ln_kernel(
    const float* __restrict__ resid, const float* __restrict__ addv,
    const float* __restrict__ g, const float* __restrict__ b,
    float* __restrict__ outf, unsigned short* __restrict__ outhi,
    unsigned short* __restrict__ outlo)
{
  int row = blockIdx.x;
  int d = threadIdx.x * 4;
  size_t base = (size_t)row * Dm + d;
  float4 v = *(const float4*)(resid + base);
  if (addv){
    float4 a = *(const float4*)(addv + base);
    v.x += a.x; v.y += a.y; v.z += a.z; v.w += a.w;
  }
  float sum = v.x + v.y + v.z + v.w;
  float sq  = v.x*v.x + v.y*v.y + v.z*v.z + v.w*v.w;
  #pragma unroll
  for (int off = 32; off; off >>= 1){
    sum += __shfl_down(sum, off, 64);
    sq  += __shfl_down(sq,  off, 64);
  }
  __shared__ float red[4][2];
  __shared__ float bc[2];
  int lane = threadIdx.x & 63, wv = threadIdx.x >> 6;
  if (lane == 0){ red[wv][0] = sum; red[wv][1] = sq; }
  __syncthreads();
  if (threadIdx.x == 0){
    float st = red[0][0] + red[1][0] + red[2][0] + red[3][0];
    float qt = red[0][1] + red[1][1] + red[2][1] + red[3][1];
    float mu = st * (1.f / Dm);
    float var = qt * (1.f / Dm) - mu * mu;
    bc[0] = mu; bc[1] = rsqrtf(var + 1e-5f);
  }
  __syncthreads();
  float mu = bc[0], rs = bc[1];
  float4 gv = *(const float4*)(g + d);
  float4 bv = *(const float4*)(b + d);
  float y[4];
  y[0] = (v.x - mu) * rs * gv.x + bv.x;
  y[1] = (v.y - mu) * rs * gv.y + bv.y;
  y[2] = (v.z - mu) * rs * gv.z + bv.z;
  y[3] = (v.w - mu) * rs * gv.w + bv.w;
  if (outf) *(float4*)(outf + base) = *(float4*)y;
  if (outhi){
    ushort4 h4, l4;
    unsigned short* hp = (unsigned short*)&h4;
    unsigned short* lp = (unsigned short*)&l4;
    #pragma unroll
    for (int e = 0; e < 4; e++){
      unsigned short h = f2b(y[e]);
      hp[e] = h;
      lp[e] = f2b(y[e] - b2f(h));
    }
    *(ushort4*)(outhi + base) = h4;
    *(ushort4*)(outlo + base) = l4;
  }
}

extern "C" void kernel_launch(void* const* d_in, const int* in_sizes, int n_in,
                              void* d_out, int out_size, void* d_ws, size_t ws_size,
                              hipStream_t stream)
{
  const int*   ids    = (const int*)  d_in[0];
  const float* emb    = (const float*)d_in[1];
  const float* pos    = (const float*)d_in[2];
  const float* wih    = (const float*)d_in[3];
  const float* whh    = (const float*)d_in[4];
  const float* bih    = (const float*)d_in[5];
  const float* bhh    = (const float*)d_in[6];
  const float* syn_w  = (const float*)d_in[7];
  const float* syn_b  = (const float*)d_in[8];
  const float* out_w  = (const float*)d_in[9];
  const float* out_b  = (const float*)d_in[10];
  const float* ln_g   = (const float*)d_in[11];
  const float* ln_b   = (const float*)d_in[12];
  const float* on_g   = (const float*)d_in[13];
  const float* on_b   = (const float*)d_in[14];
  const float* head_w = (const float*)d_in[15];
  const float* head_b = (const float*)d_in[16];
  float* logits = (float*)d_out;

  const size_t MB = (size_t)1 << 20;
  char* ws = (char*)d_ws;
  float*  scales   = (float*) ws;                          // 16 floats
  double* partials = (double*)(ws + 32768);                // 10*128 f64
  unsigned long long* hbuf = (unsigned long long*)(ws + 131072); // 2*2048 u64 (32KB)
  float*          hs     = (float*)         (ws + 1  * MB); // [1024,1024] f32 (4MB)
  unsigned short* xhi    = (unsigned short*)(ws + 5  * MB); // [1024,1024] bf16 (2MB)
  unsigned short* xlo    = (unsigned short*)(ws + 7  * MB); // (2MB)
  float*          outbuf = (float*)         (ws + 9  * MB); // [1024,1024] f32 (4MB)
  float*          gi     = (float*)         (ws + 13 * MB); // [1024,3072] f32 (12MB)
  unsigned short* wih_hi = (unsigned short*)(ws + 25 * MB); // [3072,1024] bf16 (6MB)
  unsigned short* wih_lo = (unsigned short*)(ws + 31 * MB); // (6MB)
  unsigned short* hhi    = (unsigned short*)(ws + 37 * MB); // [1024,4096] bf16 (8MB)
  unsigned short* hlo    = (unsigned short*)(ws + 45 * MB); // (8MB)
  unsigned short* wbuf   = (unsigned short*)(ws + 53 * MB); // up to 65.5MB (head bf16)

  bool pre_layer = ws_size >= 62  * MB;
  bool pre_head  = ws_size >= 120 * MB;

  // zero scales + partials + hbuf (tags must start at 0; h0 = 0)
  hipMemsetAsync(d_ws, 0, 163840, stream);

  // ternary scale sums: one fused kernel (f64 partials) + fixed-order reduce
  absum_all_kernel<<<1280, 256, 0, stream>>>(emb, syn_w, out_w, head_w, partials);
  scale_kernel<<<10, 128, 0, stream>>>(partials, scales);

  // x = tern(emb)[ids] + pos  -> bf16 hi/lo planes
  embed_kernel<<<1024, 256, 0, stream>>>(ids, emb, pos, scales, xhi, xlo);

  // wih -> hi/lo bf16 planes, then gi = x @ wih^T + bih (3-term split product)
  split_kernel<<<2048, 256, 0, stream>>>(wih, wih_hi, wih_lo, (long)(3 * Dm) * Dm / 4);
  gemm_kernel<true, false, 64><<<dim3(3072/64, 1024/64, 1), 256, 0, stream>>>(
      xhi, xlo, wih_hi, wih_lo, bih, nullptr, 0, gi, nullptr, nullptr, 1024, 3072, 1024);

  // sequential GRU -> hs (f32 residual) + xhi/xlo planes
  gru_kernel<<<64, 1024, 0, stream>>>(gi, whh, bhh, hbuf, hs, xhi, xlo);

  for (int l = 0; l < Lm; l++){
    // hidden = relu(x @ tern(syn_w)^T + syn_b) -> bf16 hi/lo planes
    if (pre_layer){
      tern_kernel<<<2048, 256, 0, stream>>>(syn_w + (size_t)l * Nm * Dm, scales + 1 + l,
                                            wbuf, (long)Nm * Dm / 4);
      gemm_kernel<false, false, 64><<<dim3(4096/64, 1024/64, 1), 256, 0, stream>>>(
          xhi, xlo, wbuf, nullptr, syn_b + (size_t)l * Nm, scales + 1 + l,
          1, nullptr, hhi, hlo, 1024, 4096, 1024);
    } else {
      gemm_kernel<false, true, 64><<<dim3(4096/64, 1024/64, 1), 256, 0, stream>>>(
          xhi, xlo, syn_w + (size_t)l * Nm * Dm, nullptr, syn_b + (size_t)l * Nm, scales + 1 + l,
          1, nullptr, hhi, hlo, 1024, 4096, 1024);
    }
    // out = hidden @ tern(out_w)^T + out_b (f32, split-K=2 atomic)
    hipMemsetAsync(outbuf, 0, (size_t)1024 * 1024 * 4, stream);
    if (pre_layer){
      tern_kernel<<<2048, 256, 0, stream>>>(out_w + (size_t)l * Dm * Nm, scales + 5 + l,
                                            wbuf, (long)Dm * Nm / 4);
      gemm_kernel<false, false, 64><<<dim3(1024/64, 1024/64, 2), 256, 0, stream>>>(
          hhi, hlo, wbuf, nullptr, out_b + (size_t)l * Dm, scales + 5 + l,
          0, outbuf, nullptr, nullptr, 1024, 1024, 4096);
    } else {
      gemm_kernel<false, true, 64><<<dim3(1024/64, 1024/64, 2), 256, 0, stream>>>(
          hhi, hlo, out_w + (size_t)l * Dm * Nm, nullptr, out_b + (size_t)l * Dm, scales + 5 + l,
          0, outbuf, nullptr, nullptr, 1024, 1024, 4096);
    }
    // x = LN(resid + out) -> hs f32 + xhi/xlo planes
    ln_kernel<<<1024, 256, 0, stream>>>(hs, outbuf, ln_g + (size_t)l * Dm, ln_b + (size_t)l * Dm,
                                        hs, xhi, xlo);
  }
  // final LN -> planes only
  ln_kernel<<<1024, 256, 0, stream>>>(hs, nullptr, on_g, on_b, nullptr, xhi, xlo);

  // logits = x @ tern(head_w)^T + head_b  (f32 -> d_out)
  // head grid = 250x8 = 2000 blocks (7.8/CU) -> lds-staged kernel pays here.
  if (pre_head){
    tern_kernel<<<2048, 256, 0, stream>>>(head_w, scales + 9, wbuf, (long)Vm * Dm / 4);
    gemm_lds_kernel<<<dim3(32000/128, 1024/128, 1), 256, 0, stream>>>(
        xhi, xlo, wbuf, head_b, scales + 9, 0, logits, 1024, 32000, 1024);
  } else {
    gemm_kernel<false, true, 128><<<dim3(32000/128, 1024/128, 1), 256, 0, stream>>>(
        xhi, xlo, head_w, nullptr, head_b, scales + 9, 0, logits, nullptr, nullptr, 1024, 32000, 1024);
  }
}

// Round 10
// 2180.204 us; speedup vs baseline: 1.5104x; 1.5104x over previous
//
#include <hip/hip_runtime.h>
#include <hip/hip_bf16.h>
#include <cstdint>
#include <cstddef>

#define Dm 1024
#define Sm 512
#define Bm 2
#define Nm 4096
#define Lm 4
#define Vm 32000

typedef __attribute__((ext_vector_type(8))) short short8;
typedef __attribute__((ext_vector_type(4))) float floatx4;

__device__ __forceinline__ unsigned short f2b(float f){
  union { float f; unsigned u; } v; v.f = f;
  unsigned r = (v.u + 0x7fffu + ((v.u >> 16) & 1u)) >> 16;
  return (unsigned short)r;
}
__device__ __forceinline__ float b2f(unsigned short h){
  union { unsigned u; float f; } v; v.u = ((unsigned)h) << 16;
  return v.f;
}

// async global->LDS, 16B per lane; LDS dest = wave-uniform base + lane*16
__device__ __forceinline__ void gload16(const unsigned short* g, unsigned short* l){
  __builtin_amdgcn_global_load_lds(
      (const __attribute__((address_space(1))) void*)g,
      (__attribute__((address_space(3))) void*)l, 16, 0, 0);
}

// ---------------- fused abs-sum for all 10 ternary weights (deterministic f64) ----------------
__global__ __launch_bounds__(256) void absum_all_kernel(
    const float* __restrict__ emb, const float* __restrict__ syn_w,
    const float* __restrict__ out_w, const float* __restrict__ head_w,
    double* __restrict__ partial)
{
  int wid = blockIdx.x >> 7;        // 0..9
  int blk = blockIdx.x & 127;
  const float* base; long n4;
  if (wid == 0){ base = emb; n4 = (long)Vm * Dm / 4; }
  else if (wid <= 4){ base = syn_w + (size_t)(wid - 1) * Nm * Dm; n4 = (long)Nm * Dm / 4; }
  else if (wid <= 8){ base = out_w + (size_t)(wid - 5) * Dm * Nm; n4 = (long)Nm * Dm / 4; }
  else { base = head_w; n4 = (long)Vm * Dm / 4; }

  long i = (long)blk * 256 + threadIdx.x;
  const long stride = 128L * 256;
  double s = 0.0;
  for (; i < n4; i += stride){
    float4 v = ((const float4*)base)[i];
    s += (double)fabsf(v.x) + (double)fabsf(v.y) + (double)fabsf(v.z) + (double)fabsf(v.w);
  }
  #pragma unroll
  for (int off = 32; off; off >>= 1) s += __shfl_down(s, off, 64);
  __shared__ double wsum[4];
  int lane = threadIdx.x & 63, wv = threadIdx.x >> 6;
  if (lane == 0) wsum[wv] = s;
  __syncthreads();
  if (threadIdx.x == 0) partial[wid * 128 + blk] = wsum[0] + wsum[1] + wsum[2] + wsum[3];
}

// one block per scale: fixed-order f64 reduce of 128 partials -> mean (f32)
__global__ __launch_bounds__(128) void scale_kernel(const double* __restrict__ partials,
                                                    float* __restrict__ scales){
  int b = blockIdx.x;
  int tid = threadIdx.x;
  __shared__ double red[128];
  red[tid] = partials[b * 128 + tid];
  __syncthreads();
  for (int off = 64; off; off >>= 1){
    if (tid < off) red[tid] += red[tid + off];
    __syncthreads();
  }
  if (tid == 0){
    double cnt = (b == 0 || b == 9) ? (double)Vm * (double)Dm : (double)Nm * (double)Dm;
    scales[b] = (float)(red[0] / cnt);
  }
}

// ---------------- ternarize weights -> bf16 (values in {-1,0,1}, exact) ----------------
__global__ __launch_bounds__(256) void tern_kernel(const float* __restrict__ w,
                                                   const float* __restrict__ smean,
                                                   unsigned short* __restrict__ out, long n4){
  float s = smean[0] + 1e-8f;
  long i = (long)blockIdx.x * blockDim.x + threadIdx.x;
  long stride = (long)gridDim.x * blockDim.x;
  for (; i < n4; i += stride){
    float4 v = ((const float4*)w)[i];
    ushort4 o;
    o.x = f2b(rintf(fminf(fmaxf(v.x / s, -1.f), 1.f)));
    o.y = f2b(rintf(fminf(fmaxf(v.y / s, -1.f), 1.f)));
    o.z = f2b(rintf(fminf(fmaxf(v.z / s, -1.f), 1.f)));
    o.w = f2b(rintf(fminf(fmaxf(v.w / s, -1.f), 1.f)));
    ((ushort4*)out)[i] = o;
  }
}

// ---------------- split f32 -> bf16 hi + lo planes ----------------
__global__ __launch_bounds__(256) void split_kernel(const float* __restrict__ w,
                                                    unsigned short* __restrict__ hi,
                                                    unsigned short* __restrict__ lo, long n4){
  long i = (long)blockIdx.x * blockDim.x + threadIdx.x;
  long stride = (long)gridDim.x * blockDim.x;
  for (; i < n4; i += stride){
    float4 v = ((const float4*)w)[i];
    float f[4] = {v.x, v.y, v.z, v.w};
    ushort4 h4, l4;
    unsigned short* hp = (unsigned short*)&h4;
    unsigned short* lp = (unsigned short*)&l4;
    #pragma unroll
    for (int e = 0; e < 4; e++){
      unsigned short h = f2b(f[e]);
      hp[e] = h;
      lp[e] = f2b(f[e] - b2f(h));
    }
    ((ushort4*)hi)[i] = h4;
    ((ushort4*)lo)[i] = l4;
  }
}

// ---------------- ternary embedding + positional -> bf16 hi/lo planes ----------------
__global__ __launch_bounds__(256) void embed_kernel(
    const int* __restrict__ ids, const float* __restrict__ emb,
    const float* __restrict__ pos, const float* __restrict__ smean,
    unsigned short* __restrict__ xhi, unsigned short* __restrict__ xlo)
{
  int row = blockIdx.x;            // b*512 + s
  int sp  = row & (Sm - 1);
  int id  = ids[row];
  float s = smean[0] + 1e-8f;
  int d = threadIdx.x * 4;
  float4 wv = *(const float4*)(emb + (size_t)id * Dm + d);
  float4 pv = *(const float4*)(pos + (size_t)sp * Dm + d);
  float y[4];
  y[0] = s * rintf(fminf(fmaxf(wv.x / s, -1.f), 1.f)) + pv.x;
  y[1] = s * rintf(fminf(fmaxf(wv.y / s, -1.f), 1.f)) + pv.y;
  y[2] = s * rintf(fminf(fmaxf(wv.z / s, -1.f), 1.f)) + pv.z;
  y[3] = s * rintf(fminf(fmaxf(wv.w / s, -1.f), 1.f)) + pv.w;
  ushort4 h4, l4;
  unsigned short* hp = (unsigned short*)&h4;
  unsigned short* lp = (unsigned short*)&l4;
  #pragma unroll
  for (int e = 0; e < 4; e++){
    unsigned short h = f2b(y[e]);
    hp[e] = h;
    lp[e] = f2b(y[e] - b2f(h));
  }
  size_t base = (size_t)row * Dm + d;
  *(ushort4*)(xhi + base) = h4;
  *(ushort4*)(xlo + base) = l4;
}

// ---------------- reg-staged GEMM (BT=64/128), pre-split bf16 planes ----------------
// Used for gi/syn/out GEMMs (grids 512-1024 blocks, 2-4/CU: multi-block overlap
// regime where reg-staging beats the barrier-drain lds kernel — R6 lesson).
// split-K capped at 2 — two-addend f32 atomicAdd commutes -> deterministic.
template<bool WSPLIT, bool WF32, int BT>
__global__ __launch_bounds__(256) void gemm_kernel(
    const unsigned short* __restrict__ Ahi, const unsigned short* __restrict__ Alo,
    const void* __restrict__ Wsrc, const unsigned short* __restrict__ Wlo,
    const float* __restrict__ bias, const float* __restrict__ smean,
    int relu, float* __restrict__ outf,
    unsigned short* __restrict__ outhi, unsigned short* __restrict__ outlo,
    int M, int N, int K)
{
  constexpr int WT = BT / 2;
  constexpr int FT = WT / 16;
  constexpr int RPT = 256 / BT;
  constexpr int CPT = 32 / RPT;
  constexpr int NU  = CPT / 8;

  __shared__ unsigned short As[2][BT][40];
  __shared__ unsigned short Bs[WSPLIT ? 2 : 1][BT][40];
  int tid = threadIdx.x;
  int wave = tid >> 6, lane = tid & 63;
  int wm = wave >> 1, wn = wave & 1;
  int bm = blockIdx.y, bn = blockIdx.x;

  bool tern = (smean != nullptr);
  float s = 1.f;
  if (tern) s = smean[0] + 1e-8f;

  int arow = tid / RPT, sub = tid % RPT;
  int col0 = sub * CPT;
  const unsigned short* Agh = Ahi + (size_t)(bm * BT + arow) * K + col0;
  const unsigned short* Agl = Alo + (size_t)(bm * BT + arow) * K + col0;
  const float* Wgf = nullptr;
  const unsigned short* Wgh = nullptr;
  const unsigned short* Wgl = nullptr;
  if (WF32) Wgf = (const float*)Wsrc + (size_t)(bn * BT + arow) * K + col0;
  else {
    Wgh = (const unsigned short*)Wsrc + (size_t)(bn * BT + arow) * K + col0;
    if (WSPLIT) Wgl = Wlo + (size_t)(bn * BT + arow) * K + col0;
  }

  floatx4 acc[FT][FT];
  #pragma unroll
  for (int i = 0; i < FT; i++)
    #pragma unroll
    for (int j = 0; j < FT; j++)
      acc[i][j] = (floatx4){0.f, 0.f, 0.f, 0.f};

  int kpb = K / (int)gridDim.z;
  int k_beg = blockIdx.z * kpb;

  for (int k0 = k_beg; k0 < k_beg + kpb; k0 += 32){
    __syncthreads();
    #pragma unroll
    for (int u = 0; u < NU; u++){
      *(uint4*)&As[0][arow][col0 + u * 8] = *(const uint4*)(Agh + k0 + u * 8);
      *(uint4*)&As[1][arow][col0 + u * 8] = *(const uint4*)(Agl + k0 + u * 8);
    }
    if (WF32){
      unsigned short tmp[CPT];
      #pragma unroll
      for (int q = 0; q < CPT / 4; q++){
        float4 wv = *(const float4*)(Wgf + k0 + q * 4);
        float f[4] = {wv.x, wv.y, wv.z, wv.w};
        #pragma unroll
        for (int e = 0; e < 4; e++){
          float w = f[e];
          if (tern) w = rintf(fminf(fmaxf(w / s, -1.f), 1.f));
          tmp[q * 4 + e] = f2b(w);
        }
      }
      #pragma unroll
      for (int u = 0; u < NU; u++)
        *(uint4*)&Bs[0][arow][col0 + u * 8] = *(uint4*)&tmp[u * 8];
    } else {
      #pragma unroll
      for (int u = 0; u < NU; u++){
        *(uint4*)&Bs[0][arow][col0 + u * 8] = *(const uint4*)(Wgh + k0 + u * 8);
        if (WSPLIT)
          *(uint4*)&Bs[1][arow][col0 + u * 8] = *(const uint4*)(Wgl + k0 + u * 8);
      }
    }
    __syncthreads();

    int kq = lane >> 4, mr = lane & 15;
    short8 afh[FT], afl[FT], bfh[FT];
    #pragma unroll
    for (int i = 0; i < FT; i++){
      afh[i] = *(const short8*)&As[0][wm*WT + i*16 + mr][kq*8];
      afl[i] = *(const short8*)&As[1][wm*WT + i*16 + mr][kq*8];
    }
    #pragma unroll
    for (int j = 0; j < FT; j++) bfh[j] = *(const short8*)&Bs[0][wn*WT + j*16 + mr][kq*8];
    #pragma unroll
    for (int i = 0; i < FT; i++)
      #pragma unroll
      for (int j = 0; j < FT; j++){
        acc[i][j] = __builtin_amdgcn_mfma_f32_16x16x32_bf16(afh[i], bfh[j], acc[i][j], 0, 0, 0);
        acc[i][j] = __builtin_amdgcn_mfma_f32_16x16x32_bf16(afl[i], bfh[j], acc[i][j], 0, 0, 0);
      }
    if (WSPLIT){
      short8 bfl[FT];
      #pragma unroll
      for (int j = 0; j < FT; j++) bfl[j] = *(const short8*)&Bs[1][wn*WT + j*16 + mr][kq*8];
      #pragma unroll
      for (int i = 0; i < FT; i++)
        #pragma unroll
        for (int j = 0; j < FT; j++)
          acc[i][j] = __builtin_amdgcn_mfma_f32_16x16x32_bf16(afh[i], bfl[j], acc[i][j], 0, 0, 0);
    }
  }

  bool split = (gridDim.z > 1);
  bool addb = (blockIdx.z == 0);
  int cr = lane >> 4, cc = lane & 15;
  #pragma unroll
  for (int j = 0; j < FT; j++){
    int col = bn * BT + wn * WT + j * 16 + cc;
    float bv = (bias && addb) ? bias[col] : 0.f;
    #pragma unroll
    for (int i = 0; i < FT; i++){
      #pragma unroll
      for (int r = 0; r < 4; r++){
        int row = bm * BT + wm * WT + i * 16 + cr * 4 + r;
        float v = acc[i][j][r] * s + bv;
        if (relu) v = fmaxf(v, 0.f);
        size_t idx = (size_t)row * N + col;
        if (outf){
          if (split) atomicAdd(outf + idx, v);
          else outf[idx] = v;
        }
        if (outhi){
          unsigned short h = f2b(v);
          outhi[idx] = h;
          outlo[idx] = f2b(v - b2f(h));
        }
      }
    }
  }
}

// ---------------- lds-staged GEMM: global_load_lds, 128x128 tile (HEAD ONLY) ----------------
// Profitable only when grid >> 256 blocks (head = 2000 blocks, 7.8/CU).
__global__ __launch_bounds__(256) void gemm_lds_kernel(
    const unsigned short* __restrict__ Ahi, const unsigned short* __restrict__ Alo,
    const unsigned short* __restrict__ Whi,
    const float* __restrict__ bias, const float* __restrict__ smean,
    int relu, float* __restrict__ outf, int M, int N, int K)
{
  __shared__ __align__(16) unsigned short lds[3 * 4096];   // planes of [128][32] bf16
  int tid = threadIdx.x;
  int wave = tid >> 6, lane = tid & 63;
  int wm = wave >> 1, wn = wave & 1;
  int bm = blockIdx.y, bn = blockIdx.x;

  float s = 1.f;
  if (smean) s = smean[0] + 1e-8f;

  int r0 = wave * 32 + (lane >> 2);
  int r1 = r0 + 16;
  int s0 = (lane & 3) ^ ((r0 >> 1) & 3);
  int s1 = (lane & 3) ^ ((r1 >> 1) & 3);
  const unsigned short* ga0 = Ahi + (size_t)(bm * 128 + r0) * K + s0 * 8;
  const unsigned short* ga1 = Ahi + (size_t)(bm * 128 + r1) * K + s1 * 8;
  const unsigned short* gl0 = Alo + (size_t)(bm * 128 + r0) * K + s0 * 8;
  const unsigned short* gl1 = Alo + (size_t)(bm * 128 + r1) * K + s1 * 8;
  const unsigned short* gw0 = Whi + (size_t)(bn * 128 + r0) * K + s0 * 8;
  const unsigned short* gw1 = Whi + (size_t)(bn * 128 + r1) * K + s1 * 8;
  unsigned short* la = &lds[wave * 1024];

  floatx4 acc[4][4];
  #pragma unroll
  for (int i = 0; i < 4; i++)
    #pragma unroll
    for (int j = 0; j < 4; j++)
      acc[i][j] = (floatx4){0.f, 0.f, 0.f, 0.f};

  for (int k0 = 0; k0 < K; k0 += 32){
    __syncthreads();
    gload16(ga0 + k0, la);
    gload16(ga1 + k0, la + 512);
    gload16(gl0 + k0, la + 4096);
    gload16(gl1 + k0, la + 4096 + 512);
    gload16(gw0 + k0, la + 8192);
    gload16(gw1 + k0, la + 8192 + 512);
    __syncthreads();

    int kq = lane >> 4, mr = lane & 15;
    short8 afh[4], afl[4], bfh[4];
    #pragma unroll
    for (int i = 0; i < 4; i++){
      int r = wm * 64 + i * 16 + mr;
      int off = r * 32 + ((kq ^ ((r >> 1) & 3)) << 3);
      afh[i] = *(const short8*)&lds[off];
      afl[i] = *(const short8*)&lds[4096 + off];
    }
    #pragma unroll
    for (int j = 0; j < 4; j++){
      int r = wn * 64 + j * 16 + mr;
      int off = r * 32 + ((kq ^ ((r >> 1) & 3)) << 3);
      bfh[j] = *(const short8*)&lds[8192 + off];
    }
    #pragma unroll
    for (int i = 0; i < 4; i++)
      #pragma unroll
      for (int j = 0; j < 4; j++){
        acc[i][j] = __builtin_amdgcn_mfma_f32_16x16x32_bf16(afh[i], bfh[j], acc[i][j], 0, 0, 0);
        acc[i][j] = __builtin_amdgcn_mfma_f32_16x16x32_bf16(afl[i], bfh[j], acc[i][j], 0, 0, 0);
      }
  }

  int cr = lane >> 4, cc = lane & 15;
  #pragma unroll
  for (int j = 0; j < 4; j++){
    int col = bn * 128 + wn * 64 + j * 16 + cc;
    float bv = bias ? bias[col] : 0.f;
    #pragma unroll
    for (int i = 0; i < 4; i++){
      #pragma unroll
      for (int r = 0; r < 4; r++){
        int row = bm * 128 + wm * 64 + i * 16 + cr * 4 + r;
        float v = acc[i][j][r] * s + bv;
        if (relu) v = fmaxf(v, 0.f);
        outf[(size_t)row * N + col] = v;
      }
    }
  }
}

// ---------------- persistent GRU over 512 steps (fence-free tagged exchange) ----------------
// 64 WGs x 1024 threads — EXACT R3/R7 structure (proven ~1400 µs over 3 runs).
// R4 lesson: poll request RATE (not poller count) loads the coherence point.
// R8/R9 lesson: producer stores MUST come from one wave (coalesced 8B x32 ->
// 2 lines); scattering them across 16 waves doubled FETCH and step latency.
// Only delta vs R7: dot-phase h reads vectorized to float4 (bit-identical
// accumulation order; chunk base c*68 floats = 272 B is 16B-aligned).
__global__ __launch_bounds__(1024) void gru_kernel(
    const float* __restrict__ gi, const float* __restrict__ whh, const float* __restrict__ bhh,
    unsigned long long* __restrict__ hbuf, float* __restrict__ hs,
    unsigned short* __restrict__ xhi, unsigned short* __restrict__ xlo)
{
  __shared__ float lds_h[2 * 1088];
  __shared__ float lds_gh[96];
  int w = blockIdx.x, tid = threadIdx.x;
  int d0 = w * 16;
  int o = tid >> 4, c = tid & 15;
  bool active = (o < 48);
  int g = o >> 4, dl = o & 15;
  int wrow = g * Dm + d0 + dl;
  float wreg[64];
  if (active){
    const float* src = whh + (size_t)wrow * Dm + c * 64;
    #pragma unroll
    for (int i = 0; i < 64; i++) wreg[i] = src[i];
  }
  float bhval = active ? bhh[wrow] : 0.f;

  int bb = tid >> 4, dd = tid & 15;
  float hprev = 0.f;

  for (int t = 0; t < Sm; t++){
    float ir = 0.f, iz = 0.f, inn = 0.f;
    if (tid < 32){
      const float* girow = gi + ((size_t)bb * Sm + t) * (3 * Dm);
      int d = d0 + dd;
      ir  = girow[d];
      iz  = girow[Dm + d];
      inn = girow[2 * Dm + d];
    }
    {
      const unsigned long long* src = hbuf + (size_t)(t & 1) * 2048 + tid * 2;
      unsigned got = 0;
      int spins = 0;
      while (got != 3u){
        #pragma unroll
        for (int q = 0; q < 2; q++){
          if (!(got & (1u << q))){
            unsigned long long wd = __hip_atomic_load(src + q, __ATOMIC_RELAXED,
                                                      __HIP_MEMORY_SCOPE_AGENT);
            if ((unsigned)(wd >> 32) == (unsigned)t){
              union { unsigned u; float f; } cv; cv.u = (unsigned)wd;
              int wi = tid * 2 + q;
              int b = wi >> 10, d = wi & 1023;
              lds_h[b * 1088 + (d >> 6) * 68 + (d & 63)] = cv.f;
              got |= 1u << q;
            }
          }
        }
        if (got != 3u){
          if (++spins > (1 << 20)) break;
          __builtin_amdgcn_s_sleep(1);
        }
      }
    }
    __syncthreads();
    if (active){
      const float* hp = lds_h + c * 68;        // 272 B base: 16B-aligned
      float a0 = 0.f, a1 = 0.f;
      #pragma unroll
      for (int q = 0; q < 16; q++){
        float4 h0 = *(const float4*)(hp + q * 4);
        float4 h1 = *(const float4*)(hp + 1088 + q * 4);
        a0 += wreg[q*4+0] * h0.x; a1 += wreg[q*4+0] * h1.x;
        a0 += wreg[q*4+1] * h0.y; a1 += wreg[q*4+1] * h1.y;
        a0 += wreg[q*4+2] * h0.z; a1 += wreg[q*4+2] * h1.z;
        a0 += wreg[q*4+3] * h0.w; a1 += wreg[q*4+3] * h1.w;
      }
      #pragma unroll
      for (int off = 8; off; off >>= 1){
        a0 += __shfl_xor(a0, off, 16);
        a1 += __shfl_xor(a1, off, 16);
      }
      if (c == 0){
        lds_gh[o]      = a0 + bhval;
        lds_gh[48 + o] = a1 + bhval;
      }
    }
    __syncthreads();
    if (tid < 32){
      float gr = lds_gh[bb * 48 + dd];
      float gz = lds_gh[bb * 48 + 16 + dd];
      float gn = lds_gh[bb * 48 + 32 + dd];
      float rr = 1.f / (1.f + expf(-(ir + gr)));
      float zz = 1.f / (1.f + expf(-(iz + gz)));
      float nn = tanhf(inn + rr * gn);
      float hnew = (1.f - zz) * nn + zz * hprev;
      hprev = hnew;
      int d = d0 + dd;
      union { float f; unsigned u; } cv; cv.f = hnew;
      unsigned long long wd = ((unsigned long long)(unsigned)(t + 1) << 32) | (unsigned long long)cv.u;
      __hip_atomic_store(hbuf + (size_t)((t + 1) & 1) * 2048 + bb * Dm + d, wd,
                         __ATOMIC_RELAXED, __HIP_MEMORY_SCOPE_AGENT);
      size_t oi = ((size_t)bb * Sm + t) * Dm + d;
      hs[oi] = hnew;
      unsigned short h = f2b(hnew);
      xhi[oi] = h;
      xlo[oi] = f2b(hnew - b2f(h));
    }
  }
}

// ---------------- layernorm (+optional residual add) -> f32 and/or bf16 planes ----------------
__global__ __launch_bounds__(256) void ln_kernel(
    const float* __restrict__ resid, const float* __restrict__ addv,
    const float* __restrict__ g, const float* __restrict__ b,
    float* __restrict__ outf, unsigned short* __restrict__ outhi,
    unsigned short* __restrict__ outlo)
{
  int row = blockIdx.x;
  int d = threadIdx.x * 4;
  size_t base = (size_t)row * Dm + d;
  float4 v = *(const float4*)(resid + base);
  if (addv){
    float4 a = *(const float4*)(addv + base);
    v.x += a.x; v.y += a.y; v.z += a.z; v.w += a.w;
  }
  float sum = v.x + v.y + v.z + v.w;
  float sq  = v.x*v.x + v.y*v.y + v.z*v.z + v.w*v.w;
  #pragma unroll
  for (int off = 32; off; off >>= 1){
    sum += __shfl_down(sum, off, 64);
    sq  += __shfl_down(sq,  off, 64);
  }
  __shared__ float red[4][2];
  __shared__ float bc[2];
  int lane = threadIdx.x & 63, wv = threadIdx.x >> 6;
  if (lane == 0){ red[wv][0] = sum; red[wv][1] = sq; }
  __syncthreads();
  if (threadIdx.x == 0){
    float st = red[0][0] + red[1][0] + red[2][0] + red[3][0];
    float qt = red[0][1] + red[1][1] + red[2][1] + red[3][1];
    float mu = st * (1.f / Dm);
    float var = qt * (1.f / Dm) - mu * mu;
    bc[0] = mu; bc[1] = rsqrtf(var + 1e-5f);
  }
  __syncthreads();
  float mu = bc[0], rs = bc[1];
  float4 gv = *(const float4*)(g + d);
  float4 bv = *(const float4*)(b + d);
  float y[4];
  y[0] = (v.x - mu) * rs * gv.x + bv.x;
  y[1] = (v.y - mu) * rs * gv.y + bv.y;
  y[2] = (v.z - mu) * rs * gv.z + bv.z;
  y[3] = (v.w - mu) * rs * gv.w + bv.w;
  if (outf) *(float4*)(outf + base) = *(float4*)y;
  if (outhi){
    ushort4 h4, l4;
    unsigned short* hp = (unsigned short*)&h4;
    unsigned short* lp = (unsigned short*)&l4;
    #pragma unroll
    for (int e = 0; e < 4; e++){
      unsigned short h = f2b(y[e]);
      hp[e] = h;
      lp[e] = f2b(y[e] - b2f(h));
    }
    *(ushort4*)(outhi + base) = h4;
    *(ushort4*)(outlo + base) = l4;
  }
}

extern "C" void kernel_launch(void* const* d_in, const int* in_sizes, int n_in,
                              void* d_out, int out_size, void* d_ws, size_t ws_size,
                              hipStream_t stream)
{
  const int*   ids    = (const int*)  d_in[0];
  const float* emb    = (const float*)d_in[1];
  const float* pos    = (const float*)d_in[2];
  const float* wih    = (const float*)d_in[3];
  const float* whh    = (const float*)d_in[4];
  const float* bih    = (const float*)d_in[5];
  const float* bhh    = (const float*)d_in[6];
  const float* syn_w  = (const float*)d_in[7];
  const float* syn_b  = (const float*)d_in[8];
  const float* out_w  = (const float*)d_in[9];
  const float* out_b  = (const float*)d_in[10];
  const float* ln_g   = (const float*)d_in[11];
  const float* ln_b   = (const float*)d_in[12];
  const float* on_g   = (const float*)d_in[13];
  const float* on_b   = (const float*)d_in[14];
  const float* head_w = (const float*)d_in[15];
  const float* head_b = (const float*)d_in[16];
  float* logits = (float*)d_out;

  const size_t MB = (size_t)1 << 20;
  char* ws = (char*)d_ws;
  float*  scales   = (float*) ws;                          // 16 floats
  double* partials = (double*)(ws + 32768);                // 10*128 f64
  unsigned long long* hbuf = (unsigned long long*)(ws + 131072); // 2*2048 u64 (32KB)
  float*          hs     = (float*)         (ws + 1  * MB); // [1024,1024] f32 (4MB)
  unsigned short* xhi    = (unsigned short*)(ws + 5  * MB); // [1024,1024] bf16 (2MB)
  unsigned short* xlo    = (unsigned short*)(ws + 7  * MB); // (2MB)
  float*          outbuf = (float*)         (ws + 9  * MB); // [1024,1024] f32 (4MB)
  float*          gi     = (float*)         (ws + 13 * MB); // [1024,3072] f32 (12MB)
  unsigned short* wih_hi = (unsigned short*)(ws + 25 * MB); // [3072,1024] bf16 (6MB)
  unsigned short* wih_lo = (unsigned short*)(ws + 31 * MB); // (6MB)
  unsigned short* hhi    = (unsigned short*)(ws + 37 * MB); // [1024,4096] bf16 (8MB)
  unsigned short* hlo    = (unsigned short*)(ws + 45 * MB); // (8MB)
  unsigned short* wbuf   = (unsigned short*)(ws + 53 * MB); // up to 65.5MB (head bf16)

  bool pre_layer = ws_size >= 62  * MB;
  bool pre_head  = ws_size >= 120 * MB;

  // zero scales + partials + hbuf (tags must start at 0; h0 = 0)
  hipMemsetAsync(d_ws, 0, 163840, stream);

  // ternary scale sums: one fused kernel (f64 partials) + fixed-order reduce
  absum_all_kernel<<<1280, 256, 0, stream>>>(emb, syn_w, out_w, head_w, partials);
  scale_kernel<<<10, 128, 0, stream>>>(partials, scales);

  // x = tern(emb)[ids] + pos  -> bf16 hi/lo planes
  embed_kernel<<<1024, 256, 0, stream>>>(ids, emb, pos, scales, xhi, xlo);

  // wih -> hi/lo bf16 planes, then gi = x @ wih^T + bih (3-term split product)
  split_kernel<<<2048, 256, 0, stream>>>(wih, wih_hi, wih_lo, (long)(3 * Dm) * Dm / 4);
  gemm_kernel<true, false, 64><<<dim3(3072/64, 1024/64, 1), 256, 0, stream>>>(
      xhi, xlo, wih_hi, wih_lo, bih, nullptr, 0, gi, nullptr, nullptr, 1024, 3072, 1024);

  // sequential GRU -> hs (f32 residual) + xhi/xlo planes
  gru_kernel<<<64, 1024, 0, stream>>>(gi, whh, bhh, hbuf, hs, xhi, xlo);

  for (int l = 0; l < Lm; l++){
    // hidden = relu(x @ tern(syn_w)^T + syn_b) -> bf16 hi/lo planes
    if (pre_layer){
      tern_kernel<<<2048, 256, 0, stream>>>(syn_w + (size_t)l * Nm * Dm, scales + 1 + l,
                                            wbuf, (long)Nm * Dm / 4);
      gemm_kernel<false, false, 64><<<dim3(4096/64, 1024/64, 1), 256, 0, stream>>>(
          xhi, xlo, wbuf, nullptr, syn_b + (size_t)l * Nm, scales + 1 + l,
          1, nullptr, hhi, hlo, 1024, 4096, 1024);
    } else {
      gemm_kernel<false, true, 64><<<dim3(4096/64, 1024/64, 1), 256, 0, stream>>>(
          xhi, xlo, syn_w + (size_t)l * Nm * Dm, nullptr, syn_b + (size_t)l * Nm, scales + 1 + l,
          1, nullptr, hhi, hlo, 1024, 4096, 1024);
    }
    // out = hidden @ tern(out_w)^T + out_b (f32, split-K=2 atomic)
    hipMemsetAsync(outbuf, 0, (size_t)1024 * 1024 * 4, stream);
    if (pre_layer){
      tern_kernel<<<2048, 256, 0, stream>>>(out_w + (size_t)l * Dm * Nm, scales + 5 + l,
                                            wbuf, (long)Dm * Nm / 4);
      gemm_kernel<false, false, 64><<<dim3(1024/64, 1024/64, 2), 256, 0, stream>>>(
          hhi, hlo, wbuf, nullptr, out_b + (size_t)l * Dm, scales + 5 + l,
          0, outbuf, nullptr, nullptr, 1024, 1024, 4096);
    } else {
      gemm_kernel<false, true, 64><<<dim3(1024/64, 1024/64, 2), 256, 0, stream>>>(
          hhi, hlo, out_w + (size_t)l * Dm * Nm, nullptr, out_b + (size_t)l * Dm, scales + 5 + l,
          0, outbuf, nullptr, nullptr, 1024, 1024, 4096);
    }
    // x = LN(resid + out) -> hs f32 + xhi/xlo planes
    ln_kernel<<<1024, 256, 0, stream>>>(hs, outbuf, ln_g + (size_t)l * Dm, ln_b + (size_t)l * Dm,
                                        hs, xhi, xlo);
  }
  // final LN -> planes only
  ln_kernel<<<1024, 256, 0, stream>>>(hs, nullptr, on_g, on_b, nullptr, xhi, xlo);

  // logits = x @ tern(head_w)^T + head_b  (f32 -> d_out)
  // head grid = 250x8 = 2000 blocks (7.8/CU) -> lds-staged kernel pays here.
  if (pre_head){
    tern_kernel<<<2048, 256, 0, stream>>>(head_w, scales + 9, wbuf, (long)Vm * Dm / 4);
    gemm_lds_kernel<<<dim3(32000/128, 1024/128, 1), 256, 0, stream>>>(
        xhi, xlo, wbuf, head_b, scales + 9, 0, logits, 1024, 32000, 1024);
  } else {
    gemm_kernel<false, true, 128><<<dim3(32000/128, 1024/128, 1), 256, 0, stream>>>(
        xhi, xlo, head_w, nullptr, head_b, scales + 9, 0, logits, nullptr, nullptr, 1024, 32000, 1024);
  }
}

// Round 11
// 2133.557 us; speedup vs baseline: 1.5434x; 1.0219x over previous
//
#include <hip/hip_runtime.h>
#include <hip/hip_bf16.h>
#include <cstdint>
#include <cstddef>

#define Dm 1024
#define Sm 512
#define Bm 2
#define Nm 4096
#define Lm 4
#define Vm 32000

typedef __attribute__((ext_vector_type(8))) short short8;
typedef __attribute__((ext_vector_type(4))) float floatx4;

struct PrepArgs {
  const float* src[9];
  unsigned short* dst[9];
  long n4[9];
  int sidx[9];
  int njobs;
};

__device__ __forceinline__ unsigned short f2b(float f){
  union { float f; unsigned u; } v; v.f = f;
  unsigned r = (v.u + 0x7fffu + ((v.u >> 16) & 1u)) >> 16;
  return (unsigned short)r;
}
__device__ __forceinline__ float b2f(unsigned short h){
  union { unsigned u; float f; } v; v.u = ((unsigned)h) << 16;
  return v.f;
}

// async global->LDS, 16B per lane; LDS dest = wave-uniform base + lane*16
__device__ __forceinline__ void gload16(const unsigned short* g, unsigned short* l){
  __builtin_amdgcn_global_load_lds(
      (const __attribute__((address_space(1))) void*)g,
      (__attribute__((address_space(3))) void*)l, 16, 0, 0);
}

// ---------------- fused abs-sum for all 10 ternary weights (deterministic f64) ----------------
__global__ __launch_bounds__(256) void absum_all_kernel(
    const float* __restrict__ emb, const float* __restrict__ syn_w,
    const float* __restrict__ out_w, const float* __restrict__ head_w,
    double* __restrict__ partial)
{
  int wid = blockIdx.x >> 7;        // 0..9
  int blk = blockIdx.x & 127;
  const float* base; long n4;
  if (wid == 0){ base = emb; n4 = (long)Vm * Dm / 4; }
  else if (wid <= 4){ base = syn_w + (size_t)(wid - 1) * Nm * Dm; n4 = (long)Nm * Dm / 4; }
  else if (wid <= 8){ base = out_w + (size_t)(wid - 5) * Dm * Nm; n4 = (long)Nm * Dm / 4; }
  else { base = head_w; n4 = (long)Vm * Dm / 4; }

  long i = (long)blk * 256 + threadIdx.x;
  const long stride = 128L * 256;
  double s = 0.0;
  for (; i < n4; i += stride){
    float4 v = ((const float4*)base)[i];
    s += (double)fabsf(v.x) + (double)fabsf(v.y) + (double)fabsf(v.z) + (double)fabsf(v.w);
  }
  #pragma unroll
  for (int off = 32; off; off >>= 1) s += __shfl_down(s, off, 64);
  __shared__ double wsum[4];
  int lane = threadIdx.x & 63, wv = threadIdx.x >> 6;
  if (lane == 0) wsum[wv] = s;
  __syncthreads();
  if (threadIdx.x == 0) partial[wid * 128 + blk] = wsum[0] + wsum[1] + wsum[2] + wsum[3];
}

// one block per scale: fixed-order f64 reduce of 128 partials -> mean (f32)
__global__ __launch_bounds__(128) void scale_kernel(const double* __restrict__ partials,
                                                    float* __restrict__ scales){
  int b = blockIdx.x;
  int tid = threadIdx.x;
  __shared__ double red[128];
  red[tid] = partials[b * 128 + tid];
  __syncthreads();
  for (int off = 64; off; off >>= 1){
    if (tid < off) red[tid] += red[tid + off];
    __syncthreads();
  }
  if (tid == 0){
    double cnt = (b == 0 || b == 9) ? (double)Vm * (double)Dm : (double)Nm * (double)Dm;
    scales[b] = (float)(red[0] / cnt);
  }
}

// ---------------- ternarize weights -> bf16 (values in {-1,0,1}, exact) ----------------
__global__ __launch_bounds__(256) void tern_kernel(const float* __restrict__ w,
                                                   const float* __restrict__ smean,
                                                   unsigned short* __restrict__ out, long n4){
  float s = smean[0] + 1e-8f;
  long i = (long)blockIdx.x * blockDim.x + threadIdx.x;
  long stride = (long)gridDim.x * blockDim.x;
  for (; i < n4; i += stride){
    float4 v = ((const float4*)w)[i];
    ushort4 o;
    o.x = f2b(rintf(fminf(fmaxf(v.x / s, -1.f), 1.f)));
    o.y = f2b(rintf(fminf(fmaxf(v.y / s, -1.f), 1.f)));
    o.z = f2b(rintf(fminf(fmaxf(v.z / s, -1.f), 1.f)));
    o.w = f2b(rintf(fminf(fmaxf(v.w / s, -1.f), 1.f)));
    ((ushort4*)out)[i] = o;
  }
}

// ---------------- split f32 -> bf16 hi + lo planes ----------------
__global__ __launch_bounds__(256) void split_kernel(const float* __restrict__ w,
                                                    unsigned short* __restrict__ hi,
                                                    unsigned short* __restrict__ lo, long n4){
  long i = (long)blockIdx.x * blockDim.x + threadIdx.x;
  long stride = (long)gridDim.x * blockDim.x;
  for (; i < n4; i += stride){
    float4 v = ((const float4*)w)[i];
    float f[4] = {v.x, v.y, v.z, v.w};
    ushort4 h4, l4;
    unsigned short* hp = (unsigned short*)&h4;
    unsigned short* lp = (unsigned short*)&l4;
    #pragma unroll
    for (int e = 0; e < 4; e++){
      unsigned short h = f2b(f[e]);
      hp[e] = h;
      lp[e] = f2b(f[e] - b2f(h));
    }
    ((ushort4*)hi)[i] = h4;
    ((ushort4*)lo)[i] = l4;
  }
}

// ---------------- ternary embedding + positional -> bf16 hi/lo planes ----------------
__global__ __launch_bounds__(256) void embed_kernel(
    const int* __restrict__ ids, const float* __restrict__ emb,
    const float* __restrict__ pos, const float* __restrict__ smean,
    unsigned short* __restrict__ xhi, unsigned short* __restrict__ xlo)
{
  int row = blockIdx.x;            // b*512 + s
  int sp  = row & (Sm - 1);
  int id  = ids[row];
  float s = smean[0] + 1e-8f;
  int d = threadIdx.x * 4;
  float4 wv = *(const float4*)(emb + (size_t)id * Dm + d);
  float4 pv = *(const float4*)(pos + (size_t)sp * Dm + d);
  float y[4];
  y[0] = s * rintf(fminf(fmaxf(wv.x / s, -1.f), 1.f)) + pv.x;
  y[1] = s * rintf(fminf(fmaxf(wv.y / s, -1.f), 1.f)) + pv.y;
  y[2] = s * rintf(fminf(fmaxf(wv.z / s, -1.f), 1.f)) + pv.z;
  y[3] = s * rintf(fminf(fmaxf(wv.w / s, -1.f), 1.f)) + pv.w;
  ushort4 h4, l4;
  unsigned short* hp = (unsigned short*)&h4;
  unsigned short* lp = (unsigned short*)&l4;
  #pragma unroll
  for (int e = 0; e < 4; e++){
    unsigned short h = f2b(y[e]);
    hp[e] = h;
    lp[e] = f2b(y[e] - b2f(h));
  }
  size_t base = (size_t)row * Dm + d;
  *(ushort4*)(xhi + base) = h4;
  *(ushort4*)(xlo + base) = l4;
}

// ---------------- reg-staged GEMM (BT=64/128), pre-split bf16 planes ----------------
// Used for gi/syn/out GEMMs (grids 512-1024 blocks, 2-4/CU: multi-block overlap
// regime where reg-staging beats the barrier-drain lds kernel — R6 lesson).
// split-K capped at 2 — two-addend f32 atomicAdd commutes -> deterministic.
template<bool WSPLIT, bool WF32, int BT>
__global__ __launch_bounds__(256) void gemm_kernel(
    const unsigned short* __restrict__ Ahi, const unsigned short* __restrict__ Alo,
    const void* __restrict__ Wsrc, const unsigned short* __restrict__ Wlo,
    const float* __restrict__ bias, const float* __restrict__ smean,
    int relu, float* __restrict__ outf,
    unsigned short* __restrict__ outhi, unsigned short* __restrict__ outlo,
    int M, int N, int K)
{
  constexpr int WT = BT / 2;
  constexpr int FT = WT / 16;
  constexpr int RPT = 256 / BT;
  constexpr int CPT = 32 / RPT;
  constexpr int NU  = CPT / 8;

  __shared__ unsigned short As[2][BT][40];
  __shared__ unsigned short Bs[WSPLIT ? 2 : 1][BT][40];
  int tid = threadIdx.x;
  int wave = tid >> 6, lane = tid & 63;
  int wm = wave >> 1, wn = wave & 1;
  int bm = blockIdx.y, bn = blockIdx.x;

  bool tern = (smean != nullptr);
  float s = 1.f;
  if (tern) s = smean[0] + 1e-8f;

  int arow = tid / RPT, sub = tid % RPT;
  int col0 = sub * CPT;
  const unsigned short* Agh = Ahi + (size_t)(bm * BT + arow) * K + col0;
  const unsigned short* Agl = Alo + (size_t)(bm * BT + arow) * K + col0;
  const float* Wgf = nullptr;
  const unsigned short* Wgh = nullptr;
  const unsigned short* Wgl = nullptr;
  if (WF32) Wgf = (const float*)Wsrc + (size_t)(bn * BT + arow) * K + col0;
  else {
    Wgh = (const unsigned short*)Wsrc + (size_t)(bn * BT + arow) * K + col0;
    if (WSPLIT) Wgl = Wlo + (size_t)(bn * BT + arow) * K + col0;
  }

  floatx4 acc[FT][FT];
  #pragma unroll
  for (int i = 0; i < FT; i++)
    #pragma unroll
    for (int j = 0; j < FT; j++)
      acc[i][j] = (floatx4){0.f, 0.f, 0.f, 0.f};

  int kpb = K / (int)gridDim.z;
  int k_beg = blockIdx.z * kpb;

  for (int k0 = k_beg; k0 < k_beg + kpb; k0 += 32){
    __syncthreads();
    #pragma unroll
    for (int u = 0; u < NU; u++){
      *(uint4*)&As[0][arow][col0 + u * 8] = *(const uint4*)(Agh + k0 + u * 8);
      *(uint4*)&As[1][arow][col0 + u * 8] = *(const uint4*)(Agl + k0 + u * 8);
    }
    if (WF32){
      unsigned short tmp[CPT];
      #pragma unroll
      for (int q = 0; q < CPT / 4; q++){
        float4 wv = *(const float4*)(Wgf + k0 + q * 4);
        float f[4] = {wv.x, wv.y, wv.z, wv.w};
        #pragma unroll
        for (int e = 0; e < 4; e++){
          float w = f[e];
          if (tern) w = rintf(fminf(fmaxf(w / s, -1.f), 1.f));
          tmp[q * 4 + e] = f2b(w);
        }
      }
      #pragma unroll
      for (int u = 0; u < NU; u++)
        *(uint4*)&Bs[0][arow][col0 + u * 8] = *(uint4*)&tmp[u * 8];
    } else {
      #pragma unroll
      for (int u = 0; u < NU; u++){
        *(uint4*)&Bs[0][arow][col0 + u * 8] = *(const uint4*)(Wgh + k0 + u * 8);
        if (WSPLIT)
          *(uint4*)&Bs[1][arow][col0 + u * 8] = *(const uint4*)(Wgl + k0 + u * 8);
      }
    }
    __syncthreads();

    int kq = lane >> 4, mr = lane & 15;
    short8 afh[FT], afl[FT], bfh[FT];
    #pragma unroll
    for (int i = 0; i < FT; i++){
      afh[i] = *(const short8*)&As[0][wm*WT + i*16 + mr][kq*8];
      afl[i] = *(const short8*)&As[1][wm*WT + i*16 + mr][kq*8];
    }
    #pragma unroll
    for (int j = 0; j < FT; j++) bfh[j] = *(const short8*)&Bs[0][wn*WT + j*16 + mr][kq*8];
    #pragma unroll
    for (int i = 0; i < FT; i++)
      #pragma unroll
      for (int j = 0; j < FT; j++){
        acc[i][j] = __builtin_amdgcn_mfma_f32_16x16x32_bf16(afh[i], bfh[j], acc[i][j], 0, 0, 0);
        acc[i][j] = __builtin_amdgcn_mfma_f32_16x16x32_bf16(afl[i], bfh[j], acc[i][j], 0, 0, 0);
      }
    if (WSPLIT){
      short8 bfl[FT];
      #pragma unroll
      for (int j = 0; j < FT; j++) bfl[j] = *(const short8*)&Bs[1][wn*WT + j*16 + mr][kq*8];
      #pragma unroll
      for (int i = 0; i < FT; i++)
        #pragma unroll
        for (int j = 0; j < FT; j++)
          acc[i][j] = __builtin_amdgcn_mfma_f32_16x16x32_bf16(afh[i], bfl[j], acc[i][j], 0, 0, 0);
    }
  }

  bool split = (gridDim.z > 1);
  bool addb = (blockIdx.z == 0);
  int cr = lane >> 4, cc = lane & 15;
  #pragma unroll
  for (int j = 0; j < FT; j++){
    int col = bn * BT + wn * WT + j * 16 + cc;
    float bv = (bias && addb) ? bias[col] : 0.f;
    #pragma unroll
    for (int i = 0; i < FT; i++){
      #pragma unroll
      for (int r = 0; r < 4; r++){
        int row = bm * BT + wm * WT + i * 16 + cr * 4 + r;
        float v = acc[i][j][r] * s + bv;
        if (relu) v = fmaxf(v, 0.f);
        size_t idx = (size_t)row * N + col;
        if (outf){
          if (split) atomicAdd(outf + idx, v);
          else outf[idx] = v;
        }
        if (outhi){
          unsigned short h = f2b(v);
          outhi[idx] = h;
          outlo[idx] = f2b(v - b2f(h));
        }
      }
    }
  }
}

// ---------------- lds-staged GEMM: global_load_lds, 128x128 tile (HEAD ONLY) ----------------
// Profitable only when grid >> 256 blocks (head = 2000 blocks, 7.8/CU).
__global__ __launch_bounds__(256) void gemm_lds_kernel(
    const unsigned short* __restrict__ Ahi, const unsigned short* __restrict__ Alo,
    const unsigned short* __restrict__ Whi,
    const float* __restrict__ bias, const float* __restrict__ smean,
    int relu, float* __restrict__ outf, int M, int N, int K)
{
  __shared__ __align__(16) unsigned short lds[3 * 4096];   // planes of [128][32] bf16
  int tid = threadIdx.x;
  int wave = tid >> 6, lane = tid & 63;
  int wm = wave >> 1, wn = wave & 1;
  int bm = blockIdx.y, bn = blockIdx.x;

  float s = 1.f;
  if (smean) s = smean[0] + 1e-8f;

  int r0 = wave * 32 + (lane >> 2);
  int r1 = r0 + 16;
  int s0 = (lane & 3) ^ ((r0 >> 1) & 3);
  int s1 = (lane & 3) ^ ((r1 >> 1) & 3);
  const unsigned short* ga0 = Ahi + (size_t)(bm * 128 + r0) * K + s0 * 8;
  const unsigned short* ga1 = Ahi + (size_t)(bm * 128 + r1) * K + s1 * 8;
  const unsigned short* gl0 = Alo + (size_t)(bm * 128 + r0) * K + s0 * 8;
  const unsigned short* gl1 = Alo + (size_t)(bm * 128 + r1) * K + s1 * 8;
  const unsigned short* gw0 = Whi + (size_t)(bn * 128 + r0) * K + s0 * 8;
  const unsigned short* gw1 = Whi + (size_t)(bn * 128 + r1) * K + s1 * 8;
  unsigned short* la = &lds[wave * 1024];

  floatx4 acc[4][4];
  #pragma unroll
  for (int i = 0; i < 4; i++)
    #pragma unroll
    for (int j = 0; j < 4; j++)
      acc[i][j] = (floatx4){0.f, 0.f, 0.f, 0.f};

  for (int k0 = 0; k0 < K; k0 += 32){
    __syncthreads();
    gload16(ga0 + k0, la);
    gload16(ga1 + k0, la + 512);
    gload16(gl0 + k0, la + 4096);
    gload16(gl1 + k0, la + 4096 + 512);
    gload16(gw0 + k0, la + 8192);
    gload16(gw1 + k0, la + 8192 + 512);
    __syncthreads();

    int kq = lane >> 4, mr = lane & 15;
    short8 afh[4], afl[4], bfh[4];
    #pragma unroll
    for (int i = 0; i < 4; i++){
      int r = wm * 64 + i * 16 + mr;
      int off = r * 32 + ((kq ^ ((r >> 1) & 3)) << 3);
      afh[i] = *(const short8*)&lds[off];
      afl[i] = *(const short8*)&lds[4096 + off];
    }
    #pragma unroll
    for (int j = 0; j < 4; j++){
      int r = wn * 64 + j * 16 + mr;
      int off = r * 32 + ((kq ^ ((r >> 1) & 3)) << 3);
      bfh[j] = *(const short8*)&lds[8192 + off];
    }
    #pragma unroll
    for (int i = 0; i < 4; i++)
      #pragma unroll
      for (int j = 0; j < 4; j++){
        acc[i][j] = __builtin_amdgcn_mfma_f32_16x16x32_bf16(afh[i], bfh[j], acc[i][j], 0, 0, 0);
        acc[i][j] = __builtin_amdgcn_mfma_f32_16x16x32_bf16(afl[i], bfh[j], acc[i][j], 0, 0, 0);
      }
  }

  int cr = lane >> 4, cc = lane & 15;
  #pragma unroll
  for (int j = 0; j < 4; j++){
    int col = bn * 128 + wn * 64 + j * 16 + cc;
    float bv = bias ? bias[col] : 0.f;
    #pragma unroll
    for (int i = 0; i < 4; i++){
      #pragma unroll
      for (int r = 0; r < 4; r++){
        int row = bm * 128 + wm * 64 + i * 16 + cr * 4 + r;
        float v = acc[i][j][r] * s + bv;
        if (relu) v = fmaxf(v, 0.f);
        outf[(size_t)row * N + col] = v;
      }
    }
  }
}

// ---------------- persistent GRU + fused weight-prep ----------------
// WGs 0..63: EXACT R3/R7 GRU structure (proven ~1400 µs over 4 runs).
//   R4 lesson: poll request RATE (not poller count) loads the coherence point.
//   R8/R9 lesson: producer stores MUST come from one wave (coalesced).
// WGs 64..: grid-stride ternarize of weights (PrepArgs jobs) during the GRU's
//   1.4ms shadow — 192 otherwise-idle CUs absorb ~265MB of tern traffic that
//   previously serialized after the GRU (same values as tern_kernel; consumers
//   are post-GRU in stream order; scales ready pre-GRU; disjoint memory).
#define NGRU 64
__global__ __launch_bounds__(1024) void gru_kernel(
    const float* __restrict__ gi, const float* __restrict__ whh, const float* __restrict__ bhh,
    unsigned long long* __restrict__ hbuf, float* __restrict__ hs,
    unsigned short* __restrict__ xhi, unsigned short* __restrict__ xlo,
    const float* __restrict__ scales, PrepArgs pa)
{
  if (blockIdx.x >= NGRU){
    long pid = blockIdx.x - NGRU;
    long stride = (long)(gridDim.x - NGRU) * 1024;
    for (int j = 0; j < pa.njobs; j++){
      float s = scales[pa.sidx[j]] + 1e-8f;
      const float4* s4 = (const float4*)pa.src[j];
      ushort4* d4 = (ushort4*)pa.dst[j];
      long n4 = pa.n4[j];
      for (long k = pid * 1024 + threadIdx.x; k < n4; k += stride){
        float4 v = s4[k];
        ushort4 o;
        o.x = f2b(rintf(fminf(fmaxf(v.x / s, -1.f), 1.f)));
        o.y = f2b(rintf(fminf(fmaxf(v.y / s, -1.f), 1.f)));
        o.z = f2b(rintf(fminf(fmaxf(v.z / s, -1.f), 1.f)));
        o.w = f2b(rintf(fminf(fmaxf(v.w / s, -1.f), 1.f)));
        d4[k] = o;
      }
    }
    return;
  }

  __shared__ float lds_h[2 * 1088];
  __shared__ float lds_gh[96];
  int w = blockIdx.x, tid = threadIdx.x;
  int d0 = w * 16;
  int o = tid >> 4, c = tid & 15;
  bool active = (o < 48);
  int g = o >> 4, dl = o & 15;
  int wrow = g * Dm + d0 + dl;
  float wreg[64];
  if (active){
    const float* src = whh + (size_t)wrow * Dm + c * 64;
    #pragma unroll
    for (int i = 0; i < 64; i++) wreg[i] = src[i];
  }
  float bhval = active ? bhh[wrow] : 0.f;

  int bb = tid >> 4, dd = tid & 15;
  float hprev = 0.f;

  for (int t = 0; t < Sm; t++){
    float ir = 0.f, iz = 0.f, inn = 0.f;
    if (tid < 32){
      const float* girow = gi + ((size_t)bb * Sm + t) * (3 * Dm);
      int d = d0 + dd;
      ir  = girow[d];
      iz  = girow[Dm + d];
      inn = girow[2 * Dm + d];
    }
    {
      const unsigned long long* src = hbuf + (size_t)(t & 1) * 2048 + tid * 2;
      unsigned got = 0;
      int spins = 0;
      while (got != 3u){
        #pragma unroll
        for (int q = 0; q < 2; q++){
          if (!(got & (1u << q))){
            unsigned long long wd = __hip_atomic_load(src + q, __ATOMIC_RELAXED,
                                                      __HIP_MEMORY_SCOPE_AGENT);
            if ((unsigned)(wd >> 32) == (unsigned)t){
              union { unsigned u; float f; } cv; cv.u = (unsigned)wd;
              int wi = tid * 2 + q;
              int b = wi >> 10, d = wi & 1023;
              lds_h[b * 1088 + (d >> 6) * 68 + (d & 63)] = cv.f;
              got |= 1u << q;
            }
          }
        }
        if (got != 3u){
          if (++spins > (1 << 20)) break;
          __builtin_amdgcn_s_sleep(1);
        }
      }
    }
    __syncthreads();
    if (active){
      const float* hp = lds_h + c * 68;        // 272 B base: 16B-aligned
      float a0 = 0.f, a1 = 0.f;
      #pragma unroll
      for (int q = 0; q < 16; q++){
        float4 h0 = *(const float4*)(hp + q * 4);
        float4 h1 = *(const float4*)(hp + 1088 + q * 4);
        a0 += wreg[q*4+0] * h0.x; a1 += wreg[q*4+0] * h1.x;
        a0 += wreg[q*4+1] * h0.y; a1 += wreg[q*4+1] * h1.y;
        a0 += wreg[q*4+2] * h0.z; a1 += wreg[q*4+2] * h1.z;
        a0 += wreg[q*4+3] * h0.w; a1 += wreg[q*4+3] * h1.w;
      }
      #pragma unroll
      for (int off = 8; off; off >>= 1){
        a0 += __shfl_xor(a0, off, 16);
        a1 += __shfl_xor(a1, off, 16);
      }
      if (c == 0){
        lds_gh[o]      = a0 + bhval;
        lds_gh[48 + o] = a1 + bhval;
      }
    }
    __syncthreads();
    if (tid < 32){
      float gr = lds_gh[bb * 48 + dd];
      float gz = lds_gh[bb * 48 + 16 + dd];
      float gn = lds_gh[bb * 48 + 32 + dd];
      float rr = 1.f / (1.f + expf(-(ir + gr)));
      float zz = 1.f / (1.f + expf(-(iz + gz)));
      float nn = tanhf(inn + rr * gn);
      float hnew = (1.f - zz) * nn + zz * hprev;
      hprev = hnew;
      int d = d0 + dd;
      union { float f; unsigned u; } cv; cv.f = hnew;
      unsigned long long wd = ((unsigned long long)(unsigned)(t + 1) << 32) | (unsigned long long)cv.u;
      __hip_atomic_store(hbuf + (size_t)((t + 1) & 1) * 2048 + bb * Dm + d, wd,
                         __ATOMIC_RELAXED, __HIP_MEMORY_SCOPE_AGENT);
      size_t oi = ((size_t)bb * Sm + t) * Dm + d;
      hs[oi] = hnew;
      unsigned short h = f2b(hnew);
      xhi[oi] = h;
      xlo[oi] = f2b(hnew - b2f(h));
    }
  }
}

// ---------------- layernorm (+optional residual add) -> f32 and/or bf16 planes ----------------
__global__ __launch_bounds__(256) void ln_kernel(
    const float* __restrict__ resid, const float* __restrict__ addv,
    const float* __restrict__ g, const float* __restrict__ b,
    float* __restrict__ outf, unsigned short* __restrict__ outhi,
    unsigned short* __restrict__ outlo)
{
  int row = blockIdx.x;
  int d = threadIdx.x * 4;
  size_t base = (size_t)row * Dm + d;
  float4 v = *(const float4*)(resid + base);
  if (addv){
    float4 a = *(const float4*)(addv + base);
    v.x += a.x; v.y += a.y; v.z += a.z; v.w += a.w;
  }
  float sum = v.x + v.y + v.z + v.w;
  float sq  = v.x*v.x + v.y*v.y + v.z*v.z + v.w*v.w;
  #pragma unroll
  for (int off = 32; off; off >>= 1){
    sum += __shfl_down(sum, off, 64);
    sq  += __shfl_down(sq,  off, 64);
  }
  __shared__ float red[4][2];
  __shared__ float bc[2];
  int lane = threadIdx.x & 63, wv = threadIdx.x >> 6;
  if (lane == 0){ red[wv][0] = sum; red[wv][1] = sq; }
  __syncthreads();
  if (threadIdx.x == 0){
    float st = red[0][0] + red[1][0] + red[2][0] + red[3][0];
    float qt = red[0][1] + red[1][1] + red[2][1] + red[3][1];
    float mu = st * (1.f / Dm);
    float var = qt * (1.f / Dm) - mu * mu;
    bc[0] = mu; bc[1] = rsqrtf(var + 1e-5f);
  }
  __syncthreads();
  float mu = bc[0], rs = bc[1];
  float4 gv = *(const float4*)(g + d);
  float4 bv = *(const float4*)(b + d);
  float y[4];
  y[0] = (v.x - mu) * rs * gv.x + bv.x;
  y[1] = (v.y - mu) * rs * gv.y + bv.y;
  y[2] = (v.z - mu) * rs * gv.z + bv.z;
  y[3] = (v.w - mu) * rs * gv.w + bv.w;
  if (outf) *(float4*)(outf + base) = *(float4*)y;
  if (outhi){
    ushort4 h4, l4;
    unsigned short* hp = (unsigned short*)&h4;
    unsigned short* lp = (unsigned short*)&l4;
    #pragma unroll
    for (int e = 0; e < 4; e++){
      unsigned short h = f2b(y[e]);
      hp[e] = h;
      lp[e] = f2b(y[e] - b2f(h));
    }
    *(ushort4*)(outhi + base) = h4;
    *(ushort4*)(outlo + base) = l4;
  }
}

extern "C" void kernel_launch(void* const* d_in, const int* in_sizes, int n_in,
                              void* d_out, int out_size, void* d_ws, size_t ws_size,
                              hipStream_t stream)
{
  const int*   ids    = (const int*)  d_in[0];
  const float* emb    = (const float*)d_in[1];
  const float* pos    = (const float*)d_in[2];
  const float* wih    = (const float*)d_in[3];
  const float* whh    = (const float*)d_in[4];
  const float* bih    = (const float*)d_in[5];
  const float* bhh    = (const float*)d_in[6];
  const float* syn_w  = (const float*)d_in[7];
  const float* syn_b  = (const float*)d_in[8];
  const float* out_w  = (const float*)d_in[9];
  const float* out_b  = (const float*)d_in[10];
  const float* ln_g   = (const float*)d_in[11];
  const float* ln_b   = (const float*)d_in[12];
  const float* on_g   = (const float*)d_in[13];
  const float* on_b   = (const float*)d_in[14];
  const float* head_w = (const float*)d_in[15];
  const float* head_b = (const float*)d_in[16];
  float* logits = (float*)d_out;

  const size_t MB = (size_t)1 << 20;
  char* ws = (char*)d_ws;
  float*  scales   = (float*) ws;                          // 16 floats
  double* partials = (double*)(ws + 32768);                // 10*128 f64
  unsigned long long* hbuf = (unsigned long long*)(ws + 131072); // 2*2048 u64 (32KB)
  float*          hs     = (float*)         (ws + 1  * MB); // [1024,1024] f32 (4MB)
  unsigned short* xhi    = (unsigned short*)(ws + 5  * MB); // [1024,1024] bf16 (2MB)
  unsigned short* xlo    = (unsigned short*)(ws + 7  * MB); // (2MB)
  float*          outbuf = (float*)         (ws + 9  * MB); // [1024,1024] f32 (4MB)
  float*          gi     = (float*)         (ws + 13 * MB); // [1024,3072] f32 (12MB), dead after GRU
  unsigned short* ltbuf  = (unsigned short*)(ws + 13 * MB); // 8MB, overlays dead gi (post-GRU terns)
  unsigned short* wih_hi = (unsigned short*)(ws + 25 * MB); // [3072,1024] bf16 (6MB), dead after gi GEMM
  unsigned short* wih_lo = (unsigned short*)(ws + 31 * MB); // (6MB)
  unsigned short* hhi    = (unsigned short*)(ws + 37 * MB); // [1024,4096] bf16 (8MB)
  unsigned short* hlo    = (unsigned short*)(ws + 45 * MB); // (8MB)
  unsigned short* wbuf   = (unsigned short*)(ws + 53 * MB); // 65.5MB (head bf16)

  bool pre_layer = ws_size >= 62  * MB;
  bool pre_head  = ws_size >= 120 * MB;
  bool tier1     = ws_size >= 192 * MB;   // 64MB of prepped layer weights at 120MB+

  // prep jobs (executed by gru_kernel's extra WGs during the GRU shadow)
  PrepArgs pa; pa.njobs = 0;
  unsigned short* synp[Lm] = {nullptr, nullptr, nullptr, nullptr};
  unsigned short* outp[Lm] = {nullptr, nullptr, nullptr, nullptr};
  auto addjob = [&](const float* s, unsigned short* d, long n4, int si){
    pa.src[pa.njobs] = s; pa.dst[pa.njobs] = d; pa.n4[pa.njobs] = n4; pa.sidx[pa.njobs] = si;
    pa.njobs++;
  };
  if (pre_head){
    addjob(head_w, wbuf, (long)Vm * Dm / 4, 9);            // head -> wbuf
    if (tier1){
      for (int l = 0; l < Lm; l++){
        synp[l] = (unsigned short*)(ws + 120 * MB + (size_t)l * 8 * MB);
        outp[l] = (unsigned short*)(ws + 152 * MB + (size_t)l * 8 * MB);
        addjob(syn_w + (size_t)l * Nm * Dm, synp[l], (long)Nm * Dm / 4, 1 + l);
        addjob(out_w + (size_t)l * Dm * Nm, outp[l], (long)Nm * Dm / 4, 5 + l);
      }
    } else {
      synp[0] = (unsigned short*)(ws + 25 * MB);           // dead wih region
      addjob(syn_w, synp[0], (long)Nm * Dm / 4, 1);
    }
  }

  // zero scales + partials + hbuf (tags must start at 0; h0 = 0)
  hipMemsetAsync(d_ws, 0, 163840, stream);

  // ternary scale sums: one fused kernel (f64 partials) + fixed-order reduce
  absum_all_kernel<<<1280, 256, 0, stream>>>(emb, syn_w, out_w, head_w, partials);
  scale_kernel<<<10, 128, 0, stream>>>(partials, scales);

  // x = tern(emb)[ids] + pos  -> bf16 hi/lo planes
  embed_kernel<<<1024, 256, 0, stream>>>(ids, emb, pos, scales, xhi, xlo);

  // wih -> hi/lo bf16 planes, then gi = x @ wih^T + bih (3-term split product)
  split_kernel<<<2048, 256, 0, stream>>>(wih, wih_hi, wih_lo, (long)(3 * Dm) * Dm / 4);
  gemm_kernel<true, false, 64><<<dim3(3072/64, 1024/64, 1), 256, 0, stream>>>(
      xhi, xlo, wih_hi, wih_lo, bih, nullptr, 0, gi, nullptr, nullptr, 1024, 3072, 1024);

  // sequential GRU (WGs 0-63) + fused weight-prep (WGs 64-255)
  gru_kernel<<<NGRU + 192, 1024, 0, stream>>>(gi, whh, bhh, hbuf, hs, xhi, xlo, scales, pa);

  for (int l = 0; l < Lm; l++){
    if (pre_head){
      // hidden = relu(x @ tern(syn_w)^T + syn_b) -> bf16 hi/lo planes
      unsigned short* sw = synp[l];
      if (!sw){
        tern_kernel<<<2048, 256, 0, stream>>>(syn_w + (size_t)l * Nm * Dm, scales + 1 + l,
                                              ltbuf, (long)Nm * Dm / 4);
        sw = ltbuf;
      }
      gemm_kernel<false, false, 64><<<dim3(4096/64, 1024/64, 1), 256, 0, stream>>>(
          xhi, xlo, sw, nullptr, syn_b + (size_t)l * Nm, scales + 1 + l,
          1, nullptr, hhi, hlo, 1024, 4096, 1024);
      // out = hidden @ tern(out_w)^T + out_b (f32, split-K=2 atomic)
      hipMemsetAsync(outbuf, 0, (size_t)1024 * 1024 * 4, stream);
      unsigned short* ow = outp[l];
      if (!ow){
        tern_kernel<<<2048, 256, 0, stream>>>(out_w + (size_t)l * Dm * Nm, scales + 5 + l,
                                              ltbuf, (long)Dm * Nm / 4);
        ow = ltbuf;
      }
      gemm_kernel<false, false, 64><<<dim3(1024/64, 1024/64, 2), 256, 0, stream>>>(
          hhi, hlo, ow, nullptr, out_b + (size_t)l * Dm, scales + 5 + l,
          0, outbuf, nullptr, nullptr, 1024, 1024, 4096);
    } else if (pre_layer){
      tern_kernel<<<2048, 256, 0, stream>>>(syn_w + (size_t)l * Nm * Dm, scales + 1 + l,
                                            wbuf, (long)Nm * Dm / 4);
      gemm_kernel<false, false, 64><<<dim3(4096/64, 1024/64, 1), 256, 0, stream>>>(
          xhi, xlo, wbuf, nullptr, syn_b + (size_t)l * Nm, scales + 1 + l,
          1, nullptr, hhi, hlo, 1024, 4096, 1024);
      hipMemsetAsync(outbuf, 0, (size_t)1024 * 1024 * 4, stream);
      tern_kernel<<<2048, 256, 0, stream>>>(out_w + (size_t)l * Dm * Nm, scales + 5 + l,
                                            wbuf, (long)Dm * Nm / 4);
      gemm_kernel<false, false, 64><<<dim3(1024/64, 1024/64, 2), 256, 0, stream>>>(
          hhi, hlo, wbuf, nullptr, out_b + (size_t)l * Dm, scales + 5 + l,
          0, outbuf, nullptr, nullptr, 1024, 1024, 4096);
    } else {
      gemm_kernel<false, true, 64><<<dim3(4096/64, 1024/64, 1), 256, 0, stream>>>(
          xhi, xlo, syn_w + (size_t)l * Nm * Dm, nullptr, syn_b + (size_t)l * Nm, scales + 1 + l,
          1, nullptr, hhi, hlo, 1024, 4096, 1024);
      hipMemsetAsync(outbuf, 0, (size_t)1024 * 1024 * 4, stream);
      gemm_kernel<false, true, 64><<<dim3(1024/64, 1024/64, 2), 256, 0, stream>>>(
          hhi, hlo, out_w + (size_t)l * Dm * Nm, nullptr, out_b + (size_t)l * Dm, scales + 5 + l,
          0, outbuf, nullptr, nullptr, 1024, 1024, 4096);
    }
    // x = LN(resid + out) -> hs f32 + xhi/xlo planes
    ln_kernel<<<1024, 256, 0, stream>>>(hs, outbuf, ln_g + (size_t)l * Dm, ln_b + (size_t)l * Dm,
                                        hs, xhi, xlo);
  }
  // final LN -> planes only
  ln_kernel<<<1024, 256, 0, stream>>>(hs, nullptr, on_g, on_b, nullptr, xhi, xlo);

  // logits = x @ tern(head_w)^T + head_b  (f32 -> d_out)
  // head grid = 250x8 = 2000 blocks (7.8/CU) -> lds-staged kernel pays here.
  if (pre_head){
    // head weights already prepped into wbuf during the GRU shadow
    gemm_lds_kernel<<<dim3(32000/128, 1024/128, 1), 256, 0, stream>>>(
        xhi, xlo, wbuf, head_b, scales + 9, 0, logits, 1024, 32000, 1024);
  } else {
    gemm_kernel<false, true, 128><<<dim3(32000/128, 1024/128, 1), 256, 0, stream>>>(
        xhi, xlo, head_w, nullptr, head_b, scales + 9, 0, logits, nullptr, nullptr, 1024, 32000, 1024);
  }
}

// Round 12
// 2132.189 us; speedup vs baseline: 1.5444x; 1.0006x over previous
//
#include <hip/hip_runtime.h>
#include <hip/hip_bf16.h>
#include <cstdint>
#include <cstddef>

#define Dm 1024
#define Sm 512
#define Bm 2
#define Nm 4096
#define Lm 4
#define Vm 32000

typedef __attribute__((ext_vector_type(8))) short short8;
typedef __attribute__((ext_vector_type(4))) float floatx4;

struct PrepArgs {
  const float* src[9];
  unsigned short* dst[9];
  long n4[9];
  int sidx[9];
  int njobs;
};

__device__ __forceinline__ unsigned short f2b(float f){
  union { float f; unsigned u; } v; v.f = f;
  unsigned r = (v.u + 0x7fffu + ((v.u >> 16) & 1u)) >> 16;
  return (unsigned short)r;
}
__device__ __forceinline__ float b2f(unsigned short h){
  union { unsigned u; float f; } v; v.u = ((unsigned)h) << 16;
  return v.f;
}

// async global->LDS, 16B per lane; LDS dest = wave-uniform base + lane*16
__device__ __forceinline__ void gload16(const unsigned short* g, unsigned short* l){
  __builtin_amdgcn_global_load_lds(
      (const __attribute__((address_space(1))) void*)g,
      (__attribute__((address_space(3))) void*)l, 16, 0, 0);
}

// ---------------- fused abs-sum for all 10 ternary weights (deterministic f64) ----------------
__global__ __launch_bounds__(256) void absum_all_kernel(
    const float* __restrict__ emb, const float* __restrict__ syn_w,
    const float* __restrict__ out_w, const float* __restrict__ head_w,
    double* __restrict__ partial)
{
  int wid = blockIdx.x >> 7;        // 0..9
  int blk = blockIdx.x & 127;
  const float* base; long n4;
  if (wid == 0){ base = emb; n4 = (long)Vm * Dm / 4; }
  else if (wid <= 4){ base = syn_w + (size_t)(wid - 1) * Nm * Dm; n4 = (long)Nm * Dm / 4; }
  else if (wid <= 8){ base = out_w + (size_t)(wid - 5) * Dm * Nm; n4 = (long)Nm * Dm / 4; }
  else { base = head_w; n4 = (long)Vm * Dm / 4; }

  long i = (long)blk * 256 + threadIdx.x;
  const long stride = 128L * 256;
  double s = 0.0;
  for (; i < n4; i += stride){
    float4 v = ((const float4*)base)[i];
    s += (double)fabsf(v.x) + (double)fabsf(v.y) + (double)fabsf(v.z) + (double)fabsf(v.w);
  }
  #pragma unroll
  for (int off = 32; off; off >>= 1) s += __shfl_down(s, off, 64);
  __shared__ double wsum[4];
  int lane = threadIdx.x & 63, wv = threadIdx.x >> 6;
  if (lane == 0) wsum[wv] = s;
  __syncthreads();
  if (threadIdx.x == 0) partial[wid * 128 + blk] = wsum[0] + wsum[1] + wsum[2] + wsum[3];
}

// one block per scale: fixed-order f64 reduce of 128 partials -> mean (f32)
__global__ __launch_bounds__(128) void scale_kernel(const double* __restrict__ partials,
                                                    float* __restrict__ scales){
  int b = blockIdx.x;
  int tid = threadIdx.x;
  __shared__ double red[128];
  red[tid] = partials[b * 128 + tid];
  __syncthreads();
  for (int off = 64; off; off >>= 1){
    if (tid < off) red[tid] += red[tid + off];
    __syncthreads();
  }
  if (tid == 0){
    double cnt = (b == 0 || b == 9) ? (double)Vm * (double)Dm : (double)Nm * (double)Dm;
    scales[b] = (float)(red[0] / cnt);
  }
}

// ---------------- ternarize weights -> bf16 (values in {-1,0,1}, exact) ----------------
__global__ __launch_bounds__(256) void tern_kernel(const float* __restrict__ w,
                                                   const float* __restrict__ smean,
                                                   unsigned short* __restrict__ out, long n4){
  float s = smean[0] + 1e-8f;
  long i = (long)blockIdx.x * blockDim.x + threadIdx.x;
  long stride = (long)gridDim.x * blockDim.x;
  for (; i < n4; i += stride){
    float4 v = ((const float4*)w)[i];
    ushort4 o;
    o.x = f2b(rintf(fminf(fmaxf(v.x / s, -1.f), 1.f)));
    o.y = f2b(rintf(fminf(fmaxf(v.y / s, -1.f), 1.f)));
    o.z = f2b(rintf(fminf(fmaxf(v.z / s, -1.f), 1.f)));
    o.w = f2b(rintf(fminf(fmaxf(v.w / s, -1.f), 1.f)));
    ((ushort4*)out)[i] = o;
  }
}

// ---------------- fused: ternary embedding + positional AND wih f32->hi/lo split ----------------
// blocks [0,1024): embed row; blocks [1024,2048): grid-stride split of wih.
__global__ __launch_bounds__(256) void embed_split_kernel(
    const int* __restrict__ ids, const float* __restrict__ emb,
    const float* __restrict__ pos, const float* __restrict__ smean,
    unsigned short* __restrict__ xhi, unsigned short* __restrict__ xlo,
    const float* __restrict__ wih, unsigned short* __restrict__ whi,
    unsigned short* __restrict__ wlo)
{
  if (blockIdx.x < 1024){
    int row = blockIdx.x;            // b*512 + s
    int sp  = row & (Sm - 1);
    int id  = ids[row];
    float s = smean[0] + 1e-8f;
    int d = threadIdx.x * 4;
    float4 wv = *(const float4*)(emb + (size_t)id * Dm + d);
    float4 pv = *(const float4*)(pos + (size_t)sp * Dm + d);
    float y[4];
    y[0] = s * rintf(fminf(fmaxf(wv.x / s, -1.f), 1.f)) + pv.x;
    y[1] = s * rintf(fminf(fmaxf(wv.y / s, -1.f), 1.f)) + pv.y;
    y[2] = s * rintf(fminf(fmaxf(wv.z / s, -1.f), 1.f)) + pv.z;
    y[3] = s * rintf(fminf(fmaxf(wv.w / s, -1.f), 1.f)) + pv.w;
    ushort4 h4, l4;
    unsigned short* hp = (unsigned short*)&h4;
    unsigned short* lp = (unsigned short*)&l4;
    #pragma unroll
    for (int e = 0; e < 4; e++){
      unsigned short h = f2b(y[e]);
      hp[e] = h;
      lp[e] = f2b(y[e] - b2f(h));
    }
    size_t base = (size_t)row * Dm + d;
    *(ushort4*)(xhi + base) = h4;
    *(ushort4*)(xlo + base) = l4;
  } else {
    long i = (long)(blockIdx.x - 1024) * 256 + threadIdx.x;
    const long stride = 1024L * 256;
    const long n4 = (long)(3 * Dm) * Dm / 4;
    for (; i < n4; i += stride){
      float4 v = ((const float4*)wih)[i];
      float f[4] = {v.x, v.y, v.z, v.w};
      ushort4 h4, l4;
      unsigned short* hp = (unsigned short*)&h4;
      unsigned short* lp = (unsigned short*)&l4;
      #pragma unroll
      for (int e = 0; e < 4; e++){
        unsigned short h = f2b(f[e]);
        hp[e] = h;
        lp[e] = f2b(f[e] - b2f(h));
      }
      ((ushort4*)whi)[i] = h4;
      ((ushort4*)wlo)[i] = l4;
    }
  }
}

// ---------------- reg-staged GEMM (BT=64/128), pre-split bf16 planes ----------------
// Used for gi/syn/out GEMMs (grids 512-1024 blocks, 2-4/CU: multi-block overlap
// regime where reg-staging beats the barrier-drain lds kernel — R6 lesson).
// split-K capped at 2 — two-addend f32 atomicAdd commutes -> deterministic.
template<bool WSPLIT, bool WF32, int BT>
__global__ __launch_bounds__(256) void gemm_kernel(
    const unsigned short* __restrict__ Ahi, const unsigned short* __restrict__ Alo,
    const void* __restrict__ Wsrc, const unsigned short* __restrict__ Wlo,
    const float* __restrict__ bias, const float* __restrict__ smean,
    int relu, float* __restrict__ outf,
    unsigned short* __restrict__ outhi, unsigned short* __restrict__ outlo,
    int M, int N, int K)
{
  constexpr int WT = BT / 2;
  constexpr int FT = WT / 16;
  constexpr int RPT = 256 / BT;
  constexpr int CPT = 32 / RPT;
  constexpr int NU  = CPT / 8;

  __shared__ unsigned short As[2][BT][40];
  __shared__ unsigned short Bs[WSPLIT ? 2 : 1][BT][40];
  int tid = threadIdx.x;
  int wave = tid >> 6, lane = tid & 63;
  int wm = wave >> 1, wn = wave & 1;
  int bm = blockIdx.y, bn = blockIdx.x;

  bool tern = (smean != nullptr);
  float s = 1.f;
  if (tern) s = smean[0] + 1e-8f;

  int arow = tid / RPT, sub = tid % RPT;
  int col0 = sub * CPT;
  const unsigned short* Agh = Ahi + (size_t)(bm * BT + arow) * K + col0;
  const unsigned short* Agl = Alo + (size_t)(bm * BT + arow) * K + col0;
  const float* Wgf = nullptr;
  const unsigned short* Wgh = nullptr;
  const unsigned short* Wgl = nullptr;
  if (WF32) Wgf = (const float*)Wsrc + (size_t)(bn * BT + arow) * K + col0;
  else {
    Wgh = (const unsigned short*)Wsrc + (size_t)(bn * BT + arow) * K + col0;
    if (WSPLIT) Wgl = Wlo + (size_t)(bn * BT + arow) * K + col0;
  }

  floatx4 acc[FT][FT];
  #pragma unroll
  for (int i = 0; i < FT; i++)
    #pragma unroll
    for (int j = 0; j < FT; j++)
      acc[i][j] = (floatx4){0.f, 0.f, 0.f, 0.f};

  int kpb = K / (int)gridDim.z;
  int k_beg = blockIdx.z * kpb;

  for (int k0 = k_beg; k0 < k_beg + kpb; k0 += 32){
    __syncthreads();
    #pragma unroll
    for (int u = 0; u < NU; u++){
      *(uint4*)&As[0][arow][col0 + u * 8] = *(const uint4*)(Agh + k0 + u * 8);
      *(uint4*)&As[1][arow][col0 + u * 8] = *(const uint4*)(Agl + k0 + u * 8);
    }
    if (WF32){
      unsigned short tmp[CPT];
      #pragma unroll
      for (int q = 0; q < CPT / 4; q++){
        float4 wv = *(const float4*)(Wgf + k0 + q * 4);
        float f[4] = {wv.x, wv.y, wv.z, wv.w};
        #pragma unroll
        for (int e = 0; e < 4; e++){
          float w = f[e];
          if (tern) w = rintf(fminf(fmaxf(w / s, -1.f), 1.f));
          tmp[q * 4 + e] = f2b(w);
        }
      }
      #pragma unroll
      for (int u = 0; u < NU; u++)
        *(uint4*)&Bs[0][arow][col0 + u * 8] = *(uint4*)&tmp[u * 8];
    } else {
      #pragma unroll
      for (int u = 0; u < NU; u++){
        *(uint4*)&Bs[0][arow][col0 + u * 8] = *(const uint4*)(Wgh + k0 + u * 8);
        if (WSPLIT)
          *(uint4*)&Bs[1][arow][col0 + u * 8] = *(const uint4*)(Wgl + k0 + u * 8);
      }
    }
    __syncthreads();

    int kq = lane >> 4, mr = lane & 15;
    short8 afh[FT], afl[FT], bfh[FT];
    #pragma unroll
    for (int i = 0; i < FT; i++){
      afh[i] = *(const short8*)&As[0][wm*WT + i*16 + mr][kq*8];
      afl[i] = *(const short8*)&As[1][wm*WT + i*16 + mr][kq*8];
    }
    #pragma unroll
    for (int j = 0; j < FT; j++) bfh[j] = *(const short8*)&Bs[0][wn*WT + j*16 + mr][kq*8];
    #pragma unroll
    for (int i = 0; i < FT; i++)
      #pragma unroll
      for (int j = 0; j < FT; j++){
        acc[i][j] = __builtin_amdgcn_mfma_f32_16x16x32_bf16(afh[i], bfh[j], acc[i][j], 0, 0, 0);
        acc[i][j] = __builtin_amdgcn_mfma_f32_16x16x32_bf16(afl[i], bfh[j], acc[i][j], 0, 0, 0);
      }
    if (WSPLIT){
      short8 bfl[FT];
      #pragma unroll
      for (int j = 0; j < FT; j++) bfl[j] = *(const short8*)&Bs[1][wn*WT + j*16 + mr][kq*8];
      #pragma unroll
      for (int i = 0; i < FT; i++)
        #pragma unroll
        for (int j = 0; j < FT; j++)
          acc[i][j] = __builtin_amdgcn_mfma_f32_16x16x32_bf16(afh[i], bfl[j], acc[i][j], 0, 0, 0);
    }
  }

  bool split = (gridDim.z > 1);
  bool addb = (blockIdx.z == 0);
  int cr = lane >> 4, cc = lane & 15;
  #pragma unroll
  for (int j = 0; j < FT; j++){
    int col = bn * BT + wn * WT + j * 16 + cc;
    float bv = (bias && addb) ? bias[col] : 0.f;
    #pragma unroll
    for (int i = 0; i < FT; i++){
      #pragma unroll
      for (int r = 0; r < 4; r++){
        int row = bm * BT + wm * WT + i * 16 + cr * 4 + r;
        float v = acc[i][j][r] * s + bv;
        if (relu) v = fmaxf(v, 0.f);
        size_t idx = (size_t)row * N + col;
        if (outf){
          if (split) atomicAdd(outf + idx, v);
          else outf[idx] = v;
        }
        if (outhi){
          unsigned short h = f2b(v);
          outhi[idx] = h;
          outlo[idx] = f2b(v - b2f(h));
        }
      }
    }
  }
}

// ---------------- lds-staged GEMM: global_load_lds, 128x128 tile (HEAD ONLY) ----------------
// Profitable only when grid >> 256 blocks (head = 2000 tiles, ~7.8/CU).
// XCD-chunked swizzle: 1-D grid of 8*nbm*ceil(nbn/8); with round-robin
// WG->XCD dispatch (xcd = id%8), XCD r owns panels bn ≡ r (mod 8): each 256KB
// W panel is fetched ONCE into its XCD's L2 and reused by all nbm row-blocks
// (was ~8x fetch with dim3(250,8) — panels straddled XCDs).
__global__ __launch_bounds__(256) void gemm_lds_kernel(
    const unsigned short* __restrict__ Ahi, const unsigned short* __restrict__ Alo,
    const unsigned short* __restrict__ Whi,
    const float* __restrict__ bias, const float* __restrict__ smean,
    int relu, float* __restrict__ outf, int M, int N, int K)
{
  int nbm = M / 128, nbn = N / 128;
  int id = blockIdx.x;
  int xcd = id & 7;
  int sblk = id >> 3;
  int bm = sblk % nbm;
  int q = sblk / nbm;
  int bn = xcd + 8 * q;
  if (bn >= nbn) return;

  __shared__ __align__(16) unsigned short lds[3 * 4096];   // planes of [128][32] bf16
  int tid = threadIdx.x;
  int wave = tid >> 6, lane = tid & 63;
  int wm = wave >> 1, wn = wave & 1;

  float s = 1.f;
  if (smean) s = smean[0] + 1e-8f;

  int r0 = wave * 32 + (lane >> 2);
  int r1 = r0 + 16;
  int s0 = (lane & 3) ^ ((r0 >> 1) & 3);
  int s1 = (lane & 3) ^ ((r1 >> 1) & 3);
  const unsigned short* ga0 = Ahi + (size_t)(bm * 128 + r0) * K + s0 * 8;
  const unsigned short* ga1 = Ahi + (size_t)(bm * 128 + r1) * K + s1 * 8;
  const unsigned short* gl0 = Alo + (size_t)(bm * 128 + r0) * K + s0 * 8;
  const unsigned short* gl1 = Alo + (size_t)(bm * 128 + r1) * K + s1 * 8;
  const unsigned short* gw0 = Whi + (size_t)(bn * 128 + r0) * K + s0 * 8;
  const unsigned short* gw1 = Whi + (size_t)(bn * 128 + r1) * K + s1 * 8;
  unsigned short* la = &lds[wave * 1024];

  floatx4 acc[4][4];
  #pragma unroll
  for (int i = 0; i < 4; i++)
    #pragma unroll
    for (int j = 0; j < 4; j++)
      acc[i][j] = (floatx4){0.f, 0.f, 0.f, 0.f};

  for (int k0 = 0; k0 < K; k0 += 32){
    __syncthreads();
    gload16(ga0 + k0, la);
    gload16(ga1 + k0, la + 512);
    gload16(gl0 + k0, la + 4096);
    gload16(gl1 + k0, la + 4096 + 512);
    gload16(gw0 + k0, la + 8192);
    gload16(gw1 + k0, la + 8192 + 512);
    __syncthreads();

    int kq = lane >> 4, mr = lane & 15;
    short8 afh[4], afl[4], bfh[4];
    #pragma unroll
    for (int i = 0; i < 4; i++){
      int r = wm * 64 + i * 16 + mr;
      int off = r * 32 + ((kq ^ ((r >> 1) & 3)) << 3);
      afh[i] = *(const short8*)&lds[off];
      afl[i] = *(const short8*)&lds[4096 + off];
    }
    #pragma unroll
    for (int j = 0; j < 4; j++){
      int r = wn * 64 + j * 16 + mr;
      int off = r * 32 + ((kq ^ ((r >> 1) & 3)) << 3);
      bfh[j] = *(const short8*)&lds[8192 + off];
    }
    #pragma unroll
    for (int i = 0; i < 4; i++)
      #pragma unroll
      for (int j = 0; j < 4; j++){
        acc[i][j] = __builtin_amdgcn_mfma_f32_16x16x32_bf16(afh[i], bfh[j], acc[i][j], 0, 0, 0);
        acc[i][j] = __builtin_amdgcn_mfma_f32_16x16x32_bf16(afl[i], bfh[j], acc[i][j], 0, 0, 0);
      }
  }

  int cr = lane >> 4, cc = lane & 15;
  #pragma unroll
  for (int j = 0; j < 4; j++){
    int col = bn * 128 + wn * 64 + j * 16 + cc;
    float bv = bias ? bias[col] : 0.f;
    #pragma unroll
    for (int i = 0; i < 4; i++){
      #pragma unroll
      for (int r = 0; r < 4; r++){
        int row = bm * 128 + wm * 64 + i * 16 + cr * 4 + r;
        float v = acc[i][j][r] * s + bv;
        if (relu) v = fmaxf(v, 0.f);
        outf[(size_t)row * N + col] = v;
      }
    }
  }
}

// ---------------- persistent GRU + fused weight-prep ----------------
// WGs 0..63: EXACT R3/R7 GRU structure (proven ~1400 µs over 4 runs).
//   R4 lesson: poll request RATE (not poller count) loads the coherence point.
//   R8/R9 lesson: producer stores MUST come from one wave (coalesced).
// WGs 64..: grid-stride ternarize of weights (PrepArgs jobs) during the GRU's
//   1.4ms shadow — 192 otherwise-idle CUs absorb ~265MB of tern traffic that
//   previously serialized after the GRU. (R11: tier-1 confirmed, net −46µs;
//   GRU +47µs from early-window HBM contention, acceptable.)
#define NGRU 64
__global__ __launch_bounds__(1024) void gru_kernel(
    const float* __restrict__ gi, const float* __restrict__ whh, const float* __restrict__ bhh,
    unsigned long long* __restrict__ hbuf, float* __restrict__ hs,
    unsigned short* __restrict__ xhi, unsigned short* __restrict__ xlo,
    const float* __restrict__ scales, PrepArgs pa)
{
  if (blockIdx.x >= NGRU){
    long pid = blockIdx.x - NGRU;
    long stride = (long)(gridDim.x - NGRU) * 1024;
    for (int j = 0; j < pa.njobs; j++){
      float s = scales[pa.sidx[j]] + 1e-8f;
      const float4* s4 = (const float4*)pa.src[j];
      ushort4* d4 = (ushort4*)pa.dst[j];
      long n4 = pa.n4[j];
      for (long k = pid * 1024 + threadIdx.x; k < n4; k += stride){
        float4 v = s4[k];
        ushort4 o;
        o.x = f2b(rintf(fminf(fmaxf(v.x / s, -1.f), 1.f)));
        o.y = f2b(rintf(fminf(fmaxf(v.y / s, -1.f), 1.f)));
        o.z = f2b(rintf(fminf(fmaxf(v.z / s, -1.f), 1.f)));
        o.w = f2b(rintf(fminf(fmaxf(v.w / s, -1.f), 1.f)));
        d4[k] = o;
      }
    }
    return;
  }

  __shared__ float lds_h[2 * 1088];
  __shared__ float lds_gh[96];
  int w = blockIdx.x, tid = threadIdx.x;
  int d0 = w * 16;
  int o = tid >> 4, c = tid & 15;
  bool active = (o < 48);
  int g = o >> 4, dl = o & 15;
  int wrow = g * Dm + d0 + dl;
  float wreg[64];
  if (active){
    const float* src = whh + (size_t)wrow * Dm + c * 64;
    #pragma unroll
    for (int i = 0; i < 64; i++) wreg[i] = src[i];
  }
  float bhval = active ? bhh[wrow] : 0.f;

  int bb = tid >> 4, dd = tid & 15;
  float hprev = 0.f;

  for (int t = 0; t < Sm; t++){
    float ir = 0.f, iz = 0.f, inn = 0.f;
    if (tid < 32){
      const float* girow = gi + ((size_t)bb * Sm + t) * (3 * Dm);
      int d = d0 + dd;
      ir  = girow[d];
      iz  = girow[Dm + d];
      inn = girow[2 * Dm + d];
    }
    {
      const unsigned long long* src = hbuf + (size_t)(t & 1) * 2048 + tid * 2;
      unsigned got = 0;
      int spins = 0;
      while (got != 3u){
        #pragma unroll
        for (int q = 0; q < 2; q++){
          if (!(got & (1u << q))){
            unsigned long long wd = __hip_atomic_load(src + q, __ATOMIC_RELAXED,
                                                      __HIP_MEMORY_SCOPE_AGENT);
            if ((unsigned)(wd >> 32) == (unsigned)t){
              union { unsigned u; float f; } cv; cv.u = (unsigned)wd;
              int wi = tid * 2 + q;
              int b = wi >> 10, d = wi & 1023;
              lds_h[b * 1088 + (d >> 6) * 68 + (d & 63)] = cv.f;
              got |= 1u << q;
            }
          }
        }
        if (got != 3u){
          if (++spins > (1 << 20)) break;
          __builtin_amdgcn_s_sleep(1);
        }
      }
    }
    __syncthreads();
    if (active){
      const float* hp = lds_h + c * 68;        // 272 B base: 16B-aligned
      float a0 = 0.f, a1 = 0.f;
      #pragma unroll
      for (int q = 0; q < 16; q++){
        float4 h0 = *(const float4*)(hp + q * 4);
        float4 h1 = *(const float4*)(hp + 1088 + q * 4);
        a0 += wreg[q*4+0] * h0.x; a1 += wreg[q*4+0] * h1.x;
        a0 += wreg[q*4+1] * h0.y; a1 += wreg[q*4+1] * h1.y;
        a0 += wreg[q*4+2] * h0.z; a1 += wreg[q*4+2] * h1.z;
        a0 += wreg[q*4+3] * h0.w; a1 += wreg[q*4+3] * h1.w;
      }
      #pragma unroll
      for (int off = 8; off; off >>= 1){
        a0 += __shfl_xor(a0, off, 16);
        a1 += __shfl_xor(a1, off, 16);
      }
      if (c == 0){
        lds_gh[o]      = a0 + bhval;
        lds_gh[48 + o] = a1 + bhval;
      }
    }
    __syncthreads();
    if (tid < 32){
      float gr = lds_gh[bb * 48 + dd];
      float gz = lds_gh[bb * 48 + 16 + dd];
      float gn = lds_gh[bb * 48 + 32 + dd];
      float rr = 1.f / (1.f + expf(-(ir + gr)));
      float zz = 1.f / (1.f + expf(-(iz + gz)));
      float nn = tanhf(inn + rr * gn);
      float hnew = (1.f - zz) * nn + zz * hprev;
      hprev = hnew;
      int d = d0 + dd;
      union { float f; unsigned u; } cv; cv.f = hnew;
      unsigned long long wd = ((unsigned long long)(unsigned)(t + 1) << 32) | (unsigned long long)cv.u;
      __hip_atomic_store(hbuf + (size_t)((t + 1) & 1) * 2048 + bb * Dm + d, wd,
                         __ATOMIC_RELAXED, __HIP_MEMORY_SCOPE_AGENT);
      size_t oi = ((size_t)bb * Sm + t) * Dm + d;
      hs[oi] = hnew;
      unsigned short h = f2b(hnew);
      xhi[oi] = h;
      xlo[oi] = f2b(hnew - b2f(h));
    }
  }
}

// ---------------- layernorm (+optional residual add) -> f32 and/or bf16 planes ----------------
__global__ __launch_bounds__(256) void ln_kernel(
    const float* __restrict__ resid, const float* __restrict__ addv,
    const float* __restrict__ g, const float* __restrict__ b,
    float* __restrict__ outf, unsigned short* __restrict__ outhi,
    unsigned short* __restrict__ outlo)
{
  int row = blockIdx.x;
  int d = threadIdx.x * 4;
  size_t base = (size_t)row * Dm + d;
  float4 v = *(const float4*)(resid + base);
  if (addv){
    float4 a = *(const float4*)(addv + base);
    v.x += a.x; v.y += a.y; v.z += a.z; v.w += a.w;
  }
  float sum = v.x + v.y + v.z + v.w;
  float sq  = v.x*v.x + v.y*v.y + v.z*v.z + v.w*v.w;
  #pragma unroll
  for (int off = 32; off; off >>= 1){
    sum += __shfl_down(sum, off, 64);
    sq  += __shfl_down(sq,  off, 64);
  }
  __shared__ float red[4][2];
  __shared__ float bc[2];
  int lane = threadIdx.x & 63, wv = threadIdx.x >> 6;
  if (lane == 0){ red[wv][0] = sum; red[wv][1] = sq; }
  __syncthreads();
  if (threadIdx.x == 0){
    float st = red[0][0] + red[1][0] + red[2][0] + red[3][0];
    float qt = red[0][1] + red[1][1] + red[2][1] + red[3][1];
    float mu = st * (1.f / Dm);
    float var = qt * (1.f / Dm) - mu * mu;
    bc[0] = mu; bc[1] = rsqrtf(var + 1e-5f);
  }
  __syncthreads();
  float mu = bc[0], rs = bc[1];
  float4 gv = *(const float4*)(g + d);
  float4 bv = *(const float4*)(b + d);
  float y[4];
  y[0] = (v.x - mu) * rs * gv.x + bv.x;
  y[1] = (v.y - mu) * rs * gv.y + bv.y;
  y[2] = (v.z - mu) * rs * gv.z + bv.z;
  y[3] = (v.w - mu) * rs * gv.w + bv.w;
  if (outf) *(float4*)(outf + base) = *(float4*)y;
  if (outhi){
    ushort4 h4, l4;
    unsigned short* hp = (unsigned short*)&h4;
    unsigned short* lp = (unsigned short*)&l4;
    #pragma unroll
    for (int e = 0; e < 4; e++){
      unsigned short h = f2b(y[e]);
      hp[e] = h;
      lp[e] = f2b(y[e] - b2f(h));
    }
    *(ushort4*)(outhi + base) = h4;
    *(ushort4*)(outlo + base) = l4;
  }
}

extern "C" void kernel_launch(void* const* d_in, const int* in_sizes, int n_in,
                              void* d_out, int out_size, void* d_ws, size_t ws_size,
                              hipStream_t stream)
{
  const int*   ids    = (const int*)  d_in[0];
  const float* emb    = (const float*)d_in[1];
  const float* pos    = (const float*)d_in[2];
  const float* wih    = (const float*)d_in[3];
  const float* whh    = (const float*)d_in[4];
  const float* bih    = (const float*)d_in[5];
  const float* bhh    = (const float*)d_in[6];
  const float* syn_w  = (const float*)d_in[7];
  const float* syn_b  = (const float*)d_in[8];
  const float* out_w  = (const float*)d_in[9];
  const float* out_b  = (const float*)d_in[10];
  const float* ln_g   = (const float*)d_in[11];
  const float* ln_b   = (const float*)d_in[12];
  const float* on_g   = (const float*)d_in[13];
  const float* on_b   = (const float*)d_in[14];
  const float* head_w = (const float*)d_in[15];
  const float* head_b = (const float*)d_in[16];
  float* logits = (float*)d_out;

  const size_t MB = (size_t)1 << 20;
  char* ws = (char*)d_ws;
  float*  scales   = (float*) ws;                          // 16 floats
  double* partials = (double*)(ws + 32768);                // 10*128 f64
  unsigned long long* hbuf = (unsigned long long*)(ws + 131072); // 2*2048 u64 (32KB)
  float*          hs     = (float*)         (ws + 1  * MB); // [1024,1024] f32 (4MB)
  unsigned short* xhi    = (unsigned short*)(ws + 5  * MB); // [1024,1024] bf16 (2MB)
  unsigned short* xlo    = (unsigned short*)(ws + 7  * MB); // (2MB)
  float*          outbuf = (float*)         (ws + 9  * MB); // [1024,1024] f32 (4MB)
  float*          gi     = (float*)         (ws + 13 * MB); // [1024,3072] f32 (12MB), dead after GRU
  unsigned short* ltbuf  = (unsigned short*)(ws + 13 * MB); // 8MB, overlays dead gi (post-GRU terns)
  unsigned short* wih_hi = (unsigned short*)(ws + 25 * MB); // [3072,1024] bf16 (6MB), dead after gi GEMM
  unsigned short* wih_lo = (unsigned short*)(ws + 31 * MB); // (6MB)
  unsigned short* hhi    = (unsigned short*)(ws + 37 * MB); // [1024,4096] bf16 (8MB)
  unsigned short* hlo    = (unsigned short*)(ws + 45 * MB); // (8MB)
  unsigned short* wbuf   = (unsigned short*)(ws + 53 * MB); // 65.5MB (head bf16)

  bool pre_layer = ws_size >= 62  * MB;
  bool pre_head  = ws_size >= 120 * MB;
  bool tier1     = ws_size >= 192 * MB;   // 64MB of prepped layer weights at 120MB+

  // prep jobs (executed by gru_kernel's extra WGs during the GRU shadow)
  PrepArgs pa; pa.njobs = 0;
  unsigned short* synp[Lm] = {nullptr, nullptr, nullptr, nullptr};
  unsigned short* outp[Lm] = {nullptr, nullptr, nullptr, nullptr};
  auto addjob = [&](const float* s, unsigned short* d, long n4, int si){
    pa.src[pa.njobs] = s; pa.dst[pa.njobs] = d; pa.n4[pa.njobs] = n4; pa.sidx[pa.njobs] = si;
    pa.njobs++;
  };
  if (pre_head){
    addjob(head_w, wbuf, (long)Vm * Dm / 4, 9);            // head -> wbuf
    if (tier1){
      for (int l = 0; l < Lm; l++){
        synp[l] = (unsigned short*)(ws + 120 * MB + (size_t)l * 8 * MB);
        outp[l] = (unsigned short*)(ws + 152 * MB + (size_t)l * 8 * MB);
        addjob(syn_w + (size_t)l * Nm * Dm, synp[l], (long)Nm * Dm / 4, 1 + l);
        addjob(out_w + (size_t)l * Dm * Nm, outp[l], (long)Nm * Dm / 4, 5 + l);
      }
    } else {
      synp[0] = (unsigned short*)(ws + 25 * MB);           // dead wih region
      addjob(syn_w, synp[0], (long)Nm * Dm / 4, 1);
    }
  }

  // zero scales + partials + hbuf (tags must start at 0; h0 = 0)
  hipMemsetAsync(d_ws, 0, 163840, stream);

  // ternary scale sums: one fused kernel (f64 partials) + fixed-order reduce
  absum_all_kernel<<<1280, 256, 0, stream>>>(emb, syn_w, out_w, head_w, partials);
  scale_kernel<<<10, 128, 0, stream>>>(partials, scales);

  // fused: x = tern(emb)[ids] + pos -> planes; wih -> hi/lo planes
  embed_split_kernel<<<2048, 256, 0, stream>>>(ids, emb, pos, scales, xhi, xlo,
                                               wih, wih_hi, wih_lo);

  // gi = x @ wih^T + bih (3-term split product)
  gemm_kernel<true, false, 64><<<dim3(3072/64, 1024/64, 1), 256, 0, stream>>>(
      xhi, xlo, wih_hi, wih_lo, bih, nullptr, 0, gi, nullptr, nullptr, 1024, 3072, 1024);

  // sequential GRU (WGs 0-63) + fused weight-prep (WGs 64-255)
  gru_kernel<<<NGRU + 192, 1024, 0, stream>>>(gi, whh, bhh, hbuf, hs, xhi, xlo, scales, pa);

  for (int l = 0; l < Lm; l++){
    if (pre_head){
      // hidden = relu(x @ tern(syn_w)^T + syn_b) -> bf16 hi/lo planes
      unsigned short* sw = synp[l];
      if (!sw){
        tern_kernel<<<2048, 256, 0, stream>>>(syn_w + (size_t)l * Nm * Dm, scales + 1 + l,
                                              ltbuf, (long)Nm * Dm / 4);
        sw = ltbuf;
      }
      gemm_kernel<false, false, 64><<<dim3(4096/64, 1024/64, 1), 256, 0, stream>>>(
          xhi, xlo, sw, nullptr, syn_b + (size_t)l * Nm, scales + 1 + l,
          1, nullptr, hhi, hlo, 1024, 4096, 1024);
      // out = hidden @ tern(out_w)^T + out_b (f32, split-K=2 atomic)
      hipMemsetAsync(outbuf, 0, (size_t)1024 * 1024 * 4, stream);
      unsigned short* ow = outp[l];
      if (!ow){
        tern_kernel<<<2048, 256, 0, stream>>>(out_w + (size_t)l * Dm * Nm, scales + 5 + l,
                                              ltbuf, (long)Dm * Nm / 4);
        ow = ltbuf;
      }
      gemm_kernel<false, false, 64><<<dim3(1024/64, 1024/64, 2), 256, 0, stream>>>(
          hhi, hlo, ow, nullptr, out_b + (size_t)l * Dm, scales + 5 + l,
          0, outbuf, nullptr, nullptr, 1024, 1024, 4096);
    } else if (pre_layer){
      tern_kernel<<<2048, 256, 0, stream>>>(syn_w + (size_t)l * Nm * Dm, scales + 1 + l,
                                            wbuf, (long)Nm * Dm / 4);
      gemm_kernel<false, false, 64><<<dim3(4096/64, 1024/64, 1), 256, 0, stream>>>(
          xhi, xlo, wbuf, nullptr, syn_b + (size_t)l * Nm, scales + 1 + l,
          1, nullptr, hhi, hlo, 1024, 4096, 1024);
      hipMemsetAsync(outbuf, 0, (size_t)1024 * 1024 * 4, stream);
      tern_kernel<<<2048, 256, 0, stream>>>(out_w + (size_t)l * Dm * Nm, scales + 5 + l,
                                            wbuf, (long)Dm * Nm / 4);
      gemm_kernel<false, false, 64><<<dim3(1024/64, 1024/64, 2), 256, 0, stream>>>(
          hhi, hlo, wbuf, nullptr, out_b + (size_t)l * Dm, scales + 5 + l,
          0, outbuf, nullptr, nullptr, 1024, 1024, 4096);
    } else {
      gemm_kernel<false, true, 64><<<dim3(4096/64, 1024/64, 1), 256, 0, stream>>>(
          xhi, xlo, syn_w + (size_t)l * Nm * Dm, nullptr, syn_b + (size_t)l * Nm, scales + 1 + l,
          1, nullptr, hhi, hlo, 1024, 4096, 1024);
      hipMemsetAsync(outbuf, 0, (size_t)1024 * 1024 * 4, stream);
      gemm_kernel<false, true, 64><<<dim3(1024/64, 1024/64, 2), 256, 0, stream>>>(
          hhi, hlo, out_w + (size_t)l * Dm * Nm, nullptr, out_b + (size_t)l * Dm, scales + 5 + l,
          0, outbuf, nullptr, nullptr, 1024, 1024, 4096);
    }
    // x = LN(resid + out) -> hs f32 + xhi/xlo planes
    ln_kernel<<<1024, 256, 0, stream>>>(hs, outbuf, ln_g + (size_t)l * Dm, ln_b + (size_t)l * Dm,
                                        hs, xhi, xlo);
  }
  // final LN -> planes only
  ln_kernel<<<1024, 256, 0, stream>>>(hs, nullptr, on_g, on_b, nullptr, xhi, xlo);

  // logits = x @ tern(head_w)^T + head_b  (f32 -> d_out)
  if (pre_head){
    // head weights already prepped into wbuf during the GRU shadow
    // XCD-chunked 1-D grid: 8 * (M/128) * ceil((N/128)/8) = 2048 blocks
    gemm_lds_kernel<<<2048, 256, 0, stream>>>(
        xhi, xlo, wbuf, head_b, scales + 9, 0, logits, 1024, 32000, 1024);
  } else {
    gemm_kernel<false, true, 128><<<dim3(32000/128, 1024/128, 1), 256, 0, stream>>>(
        xhi, xlo, head_w, nullptr, head_b, scales + 9, 0, logits, nullptr, nullptr, 1024, 32000, 1024);
  }
}

// Round 14
// 2128.585 us; speedup vs baseline: 1.5470x; 1.0017x over previous
//
#include <hip/hip_runtime.h>
#include <hip/hip_bf16.h>
#include <cstdint>
#include <cstddef>

#define Dm 1024
#define Sm 512
#define Bm 2
#define Nm 4096
#define Lm 4
#define Vm 32000

typedef __attribute__((ext_vector_type(8))) short short8;
typedef __attribute__((ext_vector_type(4))) float floatx4;

struct PrepArgs {
  const float* src[10];      // nullptr => zero-fill job
  unsigned short* dst[10];
  long n4[10];               // units of 4 elements (8 bytes out / 16 bytes in)
  int sidx[10];
  int njobs;
};

__device__ __forceinline__ unsigned short f2b(float f){
  union { float f; unsigned u; } v; v.f = f;
  unsigned r = (v.u + 0x7fffu + ((v.u >> 16) & 1u)) >> 16;
  return (unsigned short)r;
}
__device__ __forceinline__ float b2f(unsigned short h){
  union { unsigned u; float f; } v; v.u = ((unsigned)h) << 16;
  return v.f;
}

// async global->LDS, 16B per lane; LDS dest = wave-uniform base + lane*16
__device__ __forceinline__ void gload16(const unsigned short* g, unsigned short* l){
  __builtin_amdgcn_global_load_lds(
      (const __attribute__((address_space(1))) void*)g,
      (__attribute__((address_space(3))) void*)l, 16, 0, 0);
}

// ---------------- fused abs-sum for all 10 ternary weights (deterministic f64) ----------------
__global__ __launch_bounds__(256) void absum_all_kernel(
    const float* __restrict__ emb, const float* __restrict__ syn_w,
    const float* __restrict__ out_w, const float* __restrict__ head_w,
    double* __restrict__ partial)
{
  int wid = blockIdx.x >> 7;        // 0..9
  int blk = blockIdx.x & 127;
  const float* base; long n4;
  if (wid == 0){ base = emb; n4 = (long)Vm * Dm / 4; }
  else if (wid <= 4){ base = syn_w + (size_t)(wid - 1) * Nm * Dm; n4 = (long)Nm * Dm / 4; }
  else if (wid <= 8){ base = out_w + (size_t)(wid - 5) * Dm * Nm; n4 = (long)Nm * Dm / 4; }
  else { base = head_w; n4 = (long)Vm * Dm / 4; }

  long i = (long)blk * 256 + threadIdx.x;
  const long stride = 128L * 256;
  double s = 0.0;
  for (; i < n4; i += stride){
    float4 v = ((const float4*)base)[i];
    s += (double)fabsf(v.x) + (double)fabsf(v.y) + (double)fabsf(v.z) + (double)fabsf(v.w);
  }
  #pragma unroll
  for (int off = 32; off; off >>= 1) s += __shfl_down(s, off, 64);
  __shared__ double wsum[4];
  int lane = threadIdx.x & 63, wv = threadIdx.x >> 6;
  if (lane == 0) wsum[wv] = s;
  __syncthreads();
  if (threadIdx.x == 0) partial[wid * 128 + blk] = wsum[0] + wsum[1] + wsum[2] + wsum[3];
}

// one block per scale: fixed-order f64 reduce of 128 partials -> mean (f32)
__global__ __launch_bounds__(128) void scale_kernel(const double* __restrict__ partials,
                                                    float* __restrict__ scales){
  int b = blockIdx.x;
  int tid = threadIdx.x;
  __shared__ double red[128];
  red[tid] = partials[b * 128 + tid];
  __syncthreads();
  for (int off = 64; off; off >>= 1){
    if (tid < off) red[tid] += red[tid + off];
    __syncthreads();
  }
  if (tid == 0){
    double cnt = (b == 0 || b == 9) ? (double)Vm * (double)Dm : (double)Nm * (double)Dm;
    scales[b] = (float)(red[0] / cnt);
  }
}

// ---------------- ternarize weights -> bf16 (values in {-1,0,1}, exact) ----------------
__global__ __launch_bounds__(256) void tern_kernel(const float* __restrict__ w,
                                                   const float* __restrict__ smean,
                                                   unsigned short* __restrict__ out, long n4){
  float s = smean[0] + 1e-8f;
  long i = (long)blockIdx.x * blockDim.x + threadIdx.x;
  long stride = (long)gridDim.x * blockDim.x;
  for (; i < n4; i += stride){
    float4 v = ((const float4*)w)[i];
    ushort4 o;
    o.x = f2b(rintf(fminf(fmaxf(v.x / s, -1.f), 1.f)));
    o.y = f2b(rintf(fminf(fmaxf(v.y / s, -1.f), 1.f)));
    o.z = f2b(rintf(fminf(fmaxf(v.z / s, -1.f), 1.f)));
    o.w = f2b(rintf(fminf(fmaxf(v.w / s, -1.f), 1.f)));
    ((ushort4*)out)[i] = o;
  }
}

// ---------------- fused: ternary embedding + positional AND wih f32->hi/lo split ----------------
// blocks [0,1024): embed row; blocks [1024,2048): grid-stride split of wih.
__global__ __launch_bounds__(256) void embed_split_kernel(
    const int* __restrict__ ids, const float* __restrict__ emb,
    const float* __restrict__ pos, const float* __restrict__ smean,
    unsigned short* __restrict__ xhi, unsigned short* __restrict__ xlo,
    const float* __restrict__ wih, unsigned short* __restrict__ whi,
    unsigned short* __restrict__ wlo)
{
  if (blockIdx.x < 1024){
    int row = blockIdx.x;            // b*512 + s
    int sp  = row & (Sm - 1);
    int id  = ids[row];
    float s = smean[0] + 1e-8f;
    int d = threadIdx.x * 4;
    float4 wv = *(const float4*)(emb + (size_t)id * Dm + d);
    float4 pv = *(const float4*)(pos + (size_t)sp * Dm + d);
    float y[4];
    y[0] = s * rintf(fminf(fmaxf(wv.x / s, -1.f), 1.f)) + pv.x;
    y[1] = s * rintf(fminf(fmaxf(wv.y / s, -1.f), 1.f)) + pv.y;
    y[2] = s * rintf(fminf(fmaxf(wv.z / s, -1.f), 1.f)) + pv.z;
    y[3] = s * rintf(fminf(fmaxf(wv.w / s, -1.f), 1.f)) + pv.w;
    ushort4 h4, l4;
    unsigned short* hp = (unsigned short*)&h4;
    unsigned short* lp = (unsigned short*)&l4;
    #pragma unroll
    for (int e = 0; e < 4; e++){
      unsigned short h = f2b(y[e]);
      hp[e] = h;
      lp[e] = f2b(y[e] - b2f(h));
    }
    size_t base = (size_t)row * Dm + d;
    *(ushort4*)(xhi + base) = h4;
    *(ushort4*)(xlo + base) = l4;
  } else {
    long i = (long)(blockIdx.x - 1024) * 256 + threadIdx.x;
    const long stride = 1024L * 256;
    const long n4 = (long)(3 * Dm) * Dm / 4;
    for (; i < n4; i += stride){
      float4 v = ((const float4*)wih)[i];
      float f[4] = {v.x, v.y, v.z, v.w};
      ushort4 h4, l4;
      unsigned short* hp = (unsigned short*)&h4;
      unsigned short* lp = (unsigned short*)&l4;
      #pragma unroll
      for (int e = 0; e < 4; e++){
        unsigned short h = f2b(f[e]);
        hp[e] = h;
        lp[e] = f2b(f[e] - b2f(h));
      }
      ((ushort4*)whi)[i] = h4;
      ((ushort4*)wlo)[i] = l4;
    }
  }
}

// ---------------- reg-staged GEMM (BT=64/128), pre-split bf16 planes ----------------
// Used for gi/syn/out GEMMs (grids 512-1024 blocks, 2-4/CU: multi-block overlap
// regime where reg-staging beats the barrier-drain lds kernel — R6 lesson).
// split-K capped at 2 — two-addend f32 atomicAdd commutes -> deterministic.
template<bool WSPLIT, bool WF32, int BT>
__global__ __launch_bounds__(256) void gemm_kernel(
    const unsigned short* __restrict__ Ahi, const unsigned short* __restrict__ Alo,
    const void* __restrict__ Wsrc, const unsigned short* __restrict__ Wlo,
    const float* __restrict__ bias, const float* __restrict__ smean,
    int relu, float* __restrict__ outf,
    unsigned short* __restrict__ outhi, unsigned short* __restrict__ outlo,
    int M, int N, int K)
{
  constexpr int WT = BT / 2;
  constexpr int FT = WT / 16;
  constexpr int RPT = 256 / BT;
  constexpr int CPT = 32 / RPT;
  constexpr int NU  = CPT / 8;

  __shared__ unsigned short As[2][BT][40];
  __shared__ unsigned short Bs[WSPLIT ? 2 : 1][BT][40];
  int tid = threadIdx.x;
  int wave = tid >> 6, lane = tid & 63;
  int wm = wave >> 1, wn = wave & 1;
  int bm = blockIdx.y, bn = blockIdx.x;

  bool tern = (smean != nullptr);
  float s = 1.f;
  if (tern) s = smean[0] + 1e-8f;

  int arow = tid / RPT, sub = tid % RPT;
  int col0 = sub * CPT;
  const unsigned short* Agh = Ahi + (size_t)(bm * BT + arow) * K + col0;
  const unsigned short* Agl = Alo + (size_t)(bm * BT + arow) * K + col0;
  const float* Wgf = nullptr;
  const unsigned short* Wgh = nullptr;
  const unsigned short* Wgl = nullptr;
  if (WF32) Wgf = (const float*)Wsrc + (size_t)(bn * BT + arow) * K + col0;
  else {
    Wgh = (const unsigned short*)Wsrc + (size_t)(bn * BT + arow) * K + col0;
    if (WSPLIT) Wgl = Wlo + (size_t)(bn * BT + arow) * K + col0;
  }

  floatx4 acc[FT][FT];
  #pragma unroll
  for (int i = 0; i < FT; i++)
    #pragma unroll
    for (int j = 0; j < FT; j++)
      acc[i][j] = (floatx4){0.f, 0.f, 0.f, 0.f};

  int kpb = K / (int)gridDim.z;
  int k_beg = blockIdx.z * kpb;

  for (int k0 = k_beg; k0 < k_beg + kpb; k0 += 32){
    __syncthreads();
    #pragma unroll
    for (int u = 0; u < NU; u++){
      *(uint4*)&As[0][arow][col0 + u * 8] = *(const uint4*)(Agh + k0 + u * 8);
      *(uint4*)&As[1][arow][col0 + u * 8] = *(const uint4*)(Agl + k0 + u * 8);
    }
    if (WF32){
      unsigned short tmp[CPT];
      #pragma unroll
      for (int q = 0; q < CPT / 4; q++){
        float4 wv = *(const float4*)(Wgf + k0 + q * 4);
        float f[4] = {wv.x, wv.y, wv.z, wv.w};
        #pragma unroll
        for (int e = 0; e < 4; e++){
          float w = f[e];
          if (tern) w = rintf(fminf(fmaxf(w / s, -1.f), 1.f));
          tmp[q * 4 + e] = f2b(w);
        }
      }
      #pragma unroll
      for (int u = 0; u < NU; u++)
        *(uint4*)&Bs[0][arow][col0 + u * 8] = *(uint4*)&tmp[u * 8];
    } else {
      #pragma unroll
      for (int u = 0; u < NU; u++){
        *(uint4*)&Bs[0][arow][col0 + u * 8] = *(const uint4*)(Wgh + k0 + u * 8);
        if (WSPLIT)
          *(uint4*)&Bs[1][arow][col0 + u * 8] = *(const uint4*)(Wgl + k0 + u * 8);
      }
    }
    __syncthreads();

    int kq = lane >> 4, mr = lane & 15;
    short8 afh[FT], afl[FT], bfh[FT];
    #pragma unroll
    for (int i = 0; i < FT; i++){
      afh[i] = *(const short8*)&As[0][wm*WT + i*16 + mr][kq*8];
      afl[i] = *(const short8*)&As[1][wm*WT + i*16 + mr][kq*8];
    }
    #pragma unroll
    for (int j = 0; j < FT; j++) bfh[j] = *(const short8*)&Bs[0][wn*WT + j*16 + mr][kq*8];
    #pragma unroll
    for (int i = 0; i < FT; i++)
      #pragma unroll
      for (int j = 0; j < FT; j++){
        acc[i][j] = __builtin_amdgcn_mfma_f32_16x16x32_bf16(afh[i], bfh[j], acc[i][j], 0, 0, 0);
        acc[i][j] = __builtin_amdgcn_mfma_f32_16x16x32_bf16(afl[i], bfh[j], acc[i][j], 0, 0, 0);
      }
    if (WSPLIT){
      short8 bfl[FT];
      #pragma unroll
      for (int j = 0; j < FT; j++) bfl[j] = *(const short8*)&Bs[1][wn*WT + j*16 + mr][kq*8];
      #pragma unroll
      for (int i = 0; i < FT; i++)
        #pragma unroll
        for (int j = 0; j < FT; j++)
          acc[i][j] = __builtin_amdgcn_mfma_f32_16x16x32_bf16(afh[i], bfl[j], acc[i][j], 0, 0, 0);
    }
  }

  bool split = (gridDim.z > 1);
  bool addb = (blockIdx.z == 0);
  int cr = lane >> 4, cc = lane & 15;
  #pragma unroll
  for (int j = 0; j < FT; j++){
    int col = bn * BT + wn * WT + j * 16 + cc;
    float bv = (bias && addb) ? bias[col] : 0.f;
    #pragma unroll
    for (int i = 0; i < FT; i++){
      #pragma unroll
      for (int r = 0; r < 4; r++){
        int row = bm * BT + wm * WT + i * 16 + cr * 4 + r;
        float v = acc[i][j][r] * s + bv;
        if (relu) v = fmaxf(v, 0.f);
        size_t idx = (size_t)row * N + col;
        if (outf){
          if (split) atomicAdd(outf + idx, v);
          else outf[idx] = v;
        }
        if (outhi){
          unsigned short h = f2b(v);
          outhi[idx] = h;
          outlo[idx] = f2b(v - b2f(h));
        }
      }
    }
  }
}

// ---------------- lds-staged GEMM: global_load_lds, 128x128 tile (HEAD ONLY) ----------------
// Profitable only when grid >> 256 blocks (head = 2000 tiles, ~7.8/CU).
// XCD-chunked 1-D swizzle (R12: neutral — head W is L3-resident — kept, harmless).
__global__ __launch_bounds__(256) void gemm_lds_kernel(
    const unsigned short* __restrict__ Ahi, const unsigned short* __restrict__ Alo,
    const unsigned short* __restrict__ Whi,
    const float* __restrict__ bias, const float* __restrict__ smean,
    int relu, float* __restrict__ outf, int M, int N, int K)
{
  int nbm = M / 128, nbn = N / 128;
  int id = blockIdx.x;
  int xcd = id & 7;
  int sblk = id >> 3;
  int bm = sblk % nbm;
  int q = sblk / nbm;
  int bn = xcd + 8 * q;
  if (bn >= nbn) return;

  __shared__ __align__(16) unsigned short lds[3 * 4096];   // planes of [128][32] bf16
  int tid = threadIdx.x;
  int wave = tid >> 6, lane = tid & 63;
  int wm = wave >> 1, wn = wave & 1;

  float s = 1.f;
  if (smean) s = smean[0] + 1e-8f;

  int r0 = wave * 32 + (lane >> 2);
  int r1 = r0 + 16;
  int s0 = (lane & 3) ^ ((r0 >> 1) & 3);
  int s1 = (lane & 3) ^ ((r1 >> 1) & 3);
  const unsigned short* ga0 = Ahi + (size_t)(bm * 128 + r0) * K + s0 * 8;
  const unsigned short* ga1 = Ahi + (size_t)(bm * 128 + r1) * K + s1 * 8;
  const unsigned short* gl0 = Alo + (size_t)(bm * 128 + r0) * K + s0 * 8;
  const unsigned short* gl1 = Alo + (size_t)(bm * 128 + r1) * K + s1 * 8;
  const unsigned short* gw0 = Whi + (size_t)(bn * 128 + r0) * K + s0 * 8;
  const unsigned short* gw1 = Whi + (size_t)(bn * 128 + r1) * K + s1 * 8;
  unsigned short* la = &lds[wave * 1024];

  floatx4 acc[4][4];
  #pragma unroll
  for (int i = 0; i < 4; i++)
    #pragma unroll
    for (int j = 0; j < 4; j++)
      acc[i][j] = (floatx4){0.f, 0.f, 0.f, 0.f};

  for (int k0 = 0; k0 < K; k0 += 32){
    __syncthreads();
    gload16(ga0 + k0, la);
    gload16(ga1 + k0, la + 512);
    gload16(gl0 + k0, la + 4096);
    gload16(gl1 + k0, la + 4096 + 512);
    gload16(gw0 + k0, la + 8192);
    gload16(gw1 + k0, la + 8192 + 512);
    __syncthreads();

    int kq = lane >> 4, mr = lane & 15;
    short8 afh[4], afl[4], bfh[4];
    #pragma unroll
    for (int i = 0; i < 4; i++){
      int r = wm * 64 + i * 16 + mr;
      int off = r * 32 + ((kq ^ ((r >> 1) & 3)) << 3);
      afh[i] = *(const short8*)&lds[off];
      afl[i] = *(const short8*)&lds[4096 + off];
    }
    #pragma unroll
    for (int j = 0; j < 4; j++){
      int r = wn * 64 + j * 16 + mr;
      int off = r * 32 + ((kq ^ ((r >> 1) & 3)) << 3);
      bfh[j] = *(const short8*)&lds[8192 + off];
    }
    #pragma unroll
    for (int i = 0; i < 4; i++)
      #pragma unroll
      for (int j = 0; j < 4; j++){
        acc[i][j] = __builtin_amdgcn_mfma_f32_16x16x32_bf16(afh[i], bfh[j], acc[i][j], 0, 0, 0);
        acc[i][j] = __builtin_amdgcn_mfma_f32_16x16x32_bf16(afl[i], bfh[j], acc[i][j], 0, 0, 0);
      }
  }

  int cr = lane >> 4, cc = lane & 15;
  #pragma unroll
  for (int j = 0; j < 4; j++){
    int col = bn * 128 + wn * 64 + j * 16 + cc;
    float bv = bias ? bias[col] : 0.f;
    #pragma unroll
    for (int i = 0; i < 4; i++){
      #pragma unroll
      for (int r = 0; r < 4; r++){
        int row = bm * 128 + wm * 64 + i * 16 + cr * 4 + r;
        float v = acc[i][j][r] * s + bv;
        if (relu) v = fmaxf(v, 0.f);
        outf[(size_t)row * N + col] = v;
      }
    }
  }
}

// ---------------- persistent GRU + fused weight-prep ----------------
// WGs 0..63: EXACT R3/R7 GRU structure (proven ~1400 µs over 4 runs).
//   R4 lesson: poll request RATE (not poller count) loads the coherence point.
//   R8/R9 lesson: producer stores MUST come from one wave (coalesced).
// WGs 64..: DELAYED (~70µs of s_sleep) grid-stride prep jobs — R11 showed prep
//   traffic costs the GRU +45µs, likely front-loaded (L3 eviction of gi +
//   early-step contention); the delay lets the GRU's early steps run
//   uncontended while prep still has >1.2ms of shadow for ~80µs of work.
//   Jobs: ternarize weights (src!=null) or zero-fill (src==null, for outbufA).
#define NGRU 64
__global__ __launch_bounds__(1024) void gru_kernel(
    const float* __restrict__ gi, const float* __restrict__ whh, const float* __restrict__ bhh,
    unsigned long long* __restrict__ hbuf, float* __restrict__ hs,
    unsigned short* __restrict__ xhi, unsigned short* __restrict__ xlo,
    const float* __restrict__ scales, PrepArgs pa)
{
  if (blockIdx.x >= NGRU){
    if (pa.njobs > 0){
      for (int i = 0; i < 20; i++) __builtin_amdgcn_s_sleep(127);   // ~70µs
    }
    long pid = blockIdx.x - NGRU;
    long stride = (long)(gridDim.x - NGRU) * 1024;
    for (int j = 0; j < pa.njobs; j++){
      const float4* s4 = (const float4*)pa.src[j];
      ushort4* d4 = (ushort4*)pa.dst[j];
      long n4 = pa.n4[j];
      if (s4){
        float s = scales[pa.sidx[j]] + 1e-8f;
        for (long k = pid * 1024 + threadIdx.x; k < n4; k += stride){
          float4 v = s4[k];
          ushort4 o;
          o.x = f2b(rintf(fminf(fmaxf(v.x / s, -1.f), 1.f)));
          o.y = f2b(rintf(fminf(fmaxf(v.y / s, -1.f), 1.f)));
          o.z = f2b(rintf(fminf(fmaxf(v.z / s, -1.f), 1.f)));
          o.w = f2b(rintf(fminf(fmaxf(v.w / s, -1.f), 1.f)));
          d4[k] = o;
        }
      } else {
        ushort4 z = make_ushort4(0, 0, 0, 0);
        for (long k = pid * 1024 + threadIdx.x; k < n4; k += stride)
          d4[k] = z;
      }
    }
    return;
  }

  __shared__ float lds_h[2 * 1088];
  __shared__ float lds_gh[96];
  int w = blockIdx.x, tid = threadIdx.x;
  int d0 = w * 16;
  int o = tid >> 4, c = tid & 15;
  bool active = (o < 48);
  int g = o >> 4, dl = o & 15;
  int wrow = g * Dm + d0 + dl;
  float wreg[64];
  if (active){
    const float* src = whh + (size_t)wrow * Dm + c * 64;
    #pragma unroll
    for (int i = 0; i < 64; i++) wreg[i] = src[i];
  }
  float bhval = active ? bhh[wrow] : 0.f;

  int bb = tid >> 4, dd = tid & 15;
  float hprev = 0.f;

  for (int t = 0; t < Sm; t++){
    float ir = 0.f, iz = 0.f, inn = 0.f;
    if (tid < 32){
      const float* girow = gi + ((size_t)bb * Sm + t) * (3 * Dm);
      int d = d0 + dd;
      ir  = girow[d];
      iz  = girow[Dm + d];
      inn = girow[2 * Dm + d];
    }
    {
      const unsigned long long* src = hbuf + (size_t)(t & 1) * 2048 + tid * 2;
      unsigned got = 0;
      int spins = 0;
      while (got != 3u){
        #pragma unroll
        for (int q = 0; q < 2; q++){
          if (!(got & (1u << q))){
            unsigned long long wd = __hip_atomic_load(src + q, __ATOMIC_RELAXED,
                                                      __HIP_MEMORY_SCOPE_AGENT);
            if ((unsigned)(wd >> 32) == (unsigned)t){
              union { unsigned u; float f; } cv; cv.u = (unsigned)wd;
              int wi = tid * 2 + q;
              int b = wi >> 10, d = wi & 1023;
              lds_h[b * 1088 + (d >> 6) * 68 + (d & 63)] = cv.f;
              got |= 1u << q;
            }
          }
        }
        if (got != 3u){
          if (++spins > (1 << 20)) break;
          __builtin_amdgcn_s_sleep(1);
        }
      }
    }
    __syncthreads();
    if (active){
      const float* hp = lds_h + c * 68;        // 272 B base: 16B-aligned
      float a0 = 0.f, a1 = 0.f;
      #pragma unroll
      for (int q = 0; q < 16; q++){
        float4 h0 = *(const float4*)(hp + q * 4);
        float4 h1 = *(const float4*)(hp + 1088 + q * 4);
        a0 += wreg[q*4+0] * h0.x; a1 += wreg[q*4+0] * h1.x;
        a0 += wreg[q*4+1] * h0.y; a1 += wreg[q*4+1] * h1.y;
        a0 += wreg[q*4+2] * h0.z; a1 += wreg[q*4+2] * h1.z;
        a0 += wreg[q*4+3] * h0.w; a1 += wreg[q*4+3] * h1.w;
      }
      #pragma unroll
      for (int off = 8; off; off >>= 1){
        a0 += __shfl_xor(a0, off, 16);
        a1 += __shfl_xor(a1, off, 16);
      }
      if (c == 0){
        lds_gh[o]      = a0 + bhval;
        lds_gh[48 + o] = a1 + bhval;
      }
    }
    __syncthreads();
    if (tid < 32){
      float gr = lds_gh[bb * 48 + dd];
      float gz = lds_gh[bb * 48 + 16 + dd];
      float gn = lds_gh[bb * 48 + 32 + dd];
      float rr = 1.f / (1.f + expf(-(ir + gr)));
      float zz = 1.f / (1.f + expf(-(iz + gz)));
      float nn = tanhf(inn + rr * gn);
      float hnew = (1.f - zz) * nn + zz * hprev;
      hprev = hnew;
      int d = d0 + dd;
      union { float f; unsigned u; } cv; cv.f = hnew;
      unsigned long long wd = ((unsigned long long)(unsigned)(t + 1) << 32) | (unsigned long long)cv.u;
      __hip_atomic_store(hbuf + (size_t)((t + 1) & 1) * 2048 + bb * Dm + d, wd,
                         __ATOMIC_RELAXED, __HIP_MEMORY_SCOPE_AGENT);
      size_t oi = ((size_t)bb * Sm + t) * Dm + d;
      hs[oi] = hnew;
      unsigned short h = f2b(hnew);
      xhi[oi] = h;
      xlo[oi] = f2b(hnew - b2f(h));
    }
  }
}

// ---------------- layernorm (+optional residual add) -> f32 and/or bf16 planes ----------------
// blocks [0,1024): LN rows. blocks [1024,1280): zero-fill zbuf (4MB) — the
// NEXT layer's out-GEMM accumulator (ping-pong buffer != this LN's addv, so
// no overlap with reads; completes >=2 kernels before its consumer).
__global__ __launch_bounds__(256) void ln_kernel(
    const float* __restrict__ resid, const float* __restrict__ addv,
    const float* __restrict__ g, const float* __restrict__ b,
    float* __restrict__ outf, unsigned short* __restrict__ outhi,
    unsigned short* __restrict__ outlo, float* __restrict__ zbuf)
{
  if (blockIdx.x >= 1024){
    if (zbuf){
      long i = (long)(blockIdx.x - 1024) * 256 + threadIdx.x;
      float4 z = {0.f, 0.f, 0.f, 0.f};
      #pragma unroll
      for (int q = 0; q < 4; q++)
        ((float4*)zbuf)[i + (long)q * 65536] = z;
    }
    return;
  }
  int row = blockIdx.x;
  int d = threadIdx.x * 4;
  size_t base = (size_t)row * Dm + d;
  float4 v = *(const float4*)(resid + base);
  if (addv){
    float4 a = *(const float4*)(addv + base);
    v.x += a.x; v.y += a.y; v.z += a.z; v.w += a.w;
  }
  float sum = v.x + v.y + v.z + v.w;
  float sq  = v.x*v.x + v.y*v.y + v.z*v.z + v.w*v.w;
  #pragma unroll
  for (int off = 32; off; off >>= 1){
    sum += __shfl_down(sum, off, 64);
    sq  += __shfl_down(sq,  off, 64);
  }
  __shared__ float red[4][2];
  __shared__ float bc[2];
  int lane = threadIdx.x & 63, wv = threadIdx.x >> 6;
  if (lane == 0){ red[wv][0] = sum; red[wv][1] = sq; }
  __syncthreads();
  if (threadIdx.x == 0){
    float st = red[0][0] + red[1][0] + red[2][0] + red[3][0];
    float qt = red[0][1] + red[1][1] + red[2][1] + red[3][1];
    float mu = st * (1.f / Dm);
    float var = qt * (1.f / Dm) - mu * mu;
    bc[0] = mu; bc[1] = rsqrtf(var + 1e-5f);
  }
  __syncthreads();
  float mu = bc[0], rs = bc[1];
  float4 gv = *(const float4*)(g + d);
  float4 bv = *(const float4*)(b + d);
  float y[4];
  y[0] = (v.x - mu) * rs * gv.x + bv.x;
  y[1] = (v.y - mu) * rs * gv.y + bv.y;
  y[2] = (v.z - mu) * rs * gv.z + bv.z;
  y[3] = (v.w - mu) * rs * gv.w + bv.w;
  if (outf) *(float4*)(outf + base) = *(float4*)y;
  if (outhi){
    ushort4 h4, l4;
    unsigned short* hp = (unsigned short*)&h4;
    unsigned short* lp = (unsigned short*)&l4;
    #pragma unroll
    for (int e = 0; e < 4; e++){
      unsigned short h = f2b(y[e]);
      hp[e] = h;
      lp[e] = f2b(y[e] - b2f(h));
    }
    *(ushort4*)(outhi + base) = h4;
    *(ushort4*)(outlo + base) = l4;
  }
}

extern "C" void kernel_launch(void* const* d_in, const int* in_sizes, int n_in,
                              void* d_out, int out_size, void* d_ws, size_t ws_size,
                              hipStream_t stream)
{
  const int*   ids    = (const int*)  d_in[0];
  const float* emb    = (const float*)d_in[1];
  const float* pos    = (const float*)d_in[2];
  const float* wih    = (const float*)d_in[3];
  const float* whh    = (const float*)d_in[4];
  const float* bih    = (const float*)d_in[5];
  const float* bhh    = (const float*)d_in[6];
  const float* syn_w  = (const float*)d_in[7];
  const float* syn_b  = (const float*)d_in[8];
  const float* out_w  = (const float*)d_in[9];
  const float* out_b  = (const float*)d_in[10];
  const float* ln_g   = (const float*)d_in[11];
  const float* ln_b   = (const float*)d_in[12];
  const float* on_g   = (const float*)d_in[13];
  const float* on_b   = (const float*)d_in[14];
  const float* head_w = (const float*)d_in[15];
  const float* head_b = (const float*)d_in[16];
  float* logits = (float*)d_out;

  const size_t MB = (size_t)1 << 20;
  char* ws = (char*)d_ws;
  float*  scales   = (float*) ws;                          // 16 floats
  double* partials = (double*)(ws + 32768);                // 10*128 f64
  unsigned long long* hbuf = (unsigned long long*)(ws + 131072); // 2*2048 u64 (32KB)
  float*          hs     = (float*)         (ws + 1  * MB); // [1024,1024] f32 (4MB)
  unsigned short* xhi    = (unsigned short*)(ws + 5  * MB); // [1024,1024] bf16 (2MB)
  unsigned short* xlo    = (unsigned short*)(ws + 7  * MB); // (2MB)
  float*          outbufA = (float*)        (ws + 9  * MB); // [1024,1024] f32 (4MB)
  float*          gi     = (float*)         (ws + 13 * MB); // [1024,3072] f32 (12MB), dead after GRU
  float*          outbufB = (float*)        (ws + 13 * MB); // 4MB over dead gi (tier1 ping-pong)
  unsigned short* ltbuf  = (unsigned short*)(ws + 13 * MB); // 8MB over dead gi (tier2 terns)
  unsigned short* wih_hi = (unsigned short*)(ws + 25 * MB); // [3072,1024] bf16 (6MB), dead after gi GEMM
  unsigned short* wih_lo = (unsigned short*)(ws + 31 * MB); // (6MB)
  unsigned short* hhi    = (unsigned short*)(ws + 37 * MB); // [1024,4096] bf16 (8MB)
  unsigned short* hlo    = (unsigned short*)(ws + 45 * MB); // (8MB)
  unsigned short* wbuf   = (unsigned short*)(ws + 53 * MB); // 65.5MB (head bf16)

  bool pre_layer = ws_size >= 62  * MB;
  bool pre_head  = ws_size >= 120 * MB;
  bool tier1     = ws_size >= 192 * MB;   // 64MB of prepped layer weights at 120MB+

  // prep jobs (executed by gru_kernel's extra WGs during the GRU shadow)
  PrepArgs pa; pa.njobs = 0;
  unsigned short* synp[Lm] = {nullptr, nullptr, nullptr, nullptr};
  unsigned short* outp[Lm] = {nullptr, nullptr, nullptr, nullptr};
  auto addjob = [&](const float* s, unsigned short* d, long n4, int si){
    pa.src[pa.njobs] = s; pa.dst[pa.njobs] = d; pa.n4[pa.njobs] = n4; pa.sidx[pa.njobs] = si;
    pa.njobs++;
  };
  if (pre_head){
    addjob(head_w, wbuf, (long)Vm * Dm / 4, 9);            // head -> wbuf
    if (tier1){
      for (int l = 0; l < Lm; l++){
        synp[l] = (unsigned short*)(ws + 120 * MB + (size_t)l * 8 * MB);
        outp[l] = (unsigned short*)(ws + 152 * MB + (size_t)l * 8 * MB);
        addjob(syn_w + (size_t)l * Nm * Dm, synp[l], (long)Nm * Dm / 4, 1 + l);
        addjob(out_w + (size_t)l * Dm * Nm, outp[l], (long)Nm * Dm / 4, 5 + l);
      }
      // zero-fill outbufA (layer-0 accumulator); 4MB = 524288 ushort4-chunks
      addjob(nullptr, (unsigned short*)outbufA, (long)4 * MB / 8, 0);
    } else {
      synp[0] = (unsigned short*)(ws + 25 * MB);           // dead wih region
      addjob(syn_w, synp[0], (long)Nm * Dm / 4, 1);
    }
  }

  // zero scales + partials + hbuf (tags must start at 0; h0 = 0)
  hipMemsetAsync(d_ws, 0, 163840, stream);

  // ternary scale sums: one fused kernel (f64 partials) + fixed-order reduce
  absum_all_kernel<<<1280, 256, 0, stream>>>(emb, syn_w, out_w, head_w, partials);
  scale_kernel<<<10, 128, 0, stream>>>(partials, scales);

  // fused: x = tern(emb)[ids] + pos -> planes; wih -> hi/lo planes
  embed_split_kernel<<<2048, 256, 0, stream>>>(ids, emb, pos, scales, xhi, xlo,
                                               wih, wih_hi, wih_lo);

  // gi = x @ wih^T + bih (3-term split product)
  gemm_kernel<true, false, 64><<<dim3(3072/64, 1024/64, 1), 256, 0, stream>>>(
      xhi, xlo, wih_hi, wih_lo, bih, nullptr, 0, gi, nullptr, nullptr, 1024, 3072, 1024);

  // sequential GRU (WGs 0-63) + delayed fused weight-prep (WGs 64-255)
  gru_kernel<<<NGRU + 192, 1024, 0, stream>>>(gi, whh, bhh, hbuf, hs, xhi, xlo, scales, pa);

  for (int l = 0; l < Lm; l++){
    float* ob      = (tier1 && (l & 1)) ? outbufB : outbufA;
    float* ob_next = (tier1 && !((l + 1) & 1)) ? outbufA : outbufB;   // obuf(l+1)
    if (pre_head){
      // hidden = relu(x @ tern(syn_w)^T + syn_b) -> bf16 hi/lo planes
      unsigned short* sw = synp[l];
      if (!sw){
        tern_kernel<<<2048, 256, 0, stream>>>(syn_w + (size_t)l * Nm * Dm, scales + 1 + l,
                                              ltbuf, (long)Nm * Dm / 4);
        sw = ltbuf;
      }
      gemm_kernel<false, false, 64><<<dim3(4096/64, 1024/64, 1), 256, 0, stream>>>(
          xhi, xlo, sw, nullptr, syn_b + (size_t)l * Nm, scales + 1 + l,
          1, nullptr, hhi, hlo, 1024, 4096, 1024);
      // out = hidden @ tern(out_w)^T + out_b (f32, split-K=2 atomic)
      if (!tier1) hipMemsetAsync(ob, 0, (size_t)1024 * 1024 * 4, stream);
      unsigned short* ow = outp[l];
      if (!ow){
        tern_kernel<<<2048, 256, 0, stream>>>(out_w + (size_t)l * Dm * Nm, scales + 5 + l,
                                              ltbuf, (long)Dm * Nm / 4);
        ow = ltbuf;
      }
      gemm_kernel<false, false, 64><<<dim3(1024/64, 1024/64, 2), 256, 0, stream>>>(
          hhi, hlo, ow, nullptr, out_b + (size_t)l * Dm, scales + 5 + l,
          0, ob, nullptr, nullptr, 1024, 1024, 4096);
    } else if (pre_layer){
      tern_kernel<<<2048, 256, 0, stream>>>(syn_w + (size_t)l * Nm * Dm, scales + 1 + l,
                                            wbuf, (long)Nm * Dm / 4);
      gemm_kernel<false, false, 64><<<dim3(4096/64, 1024/64, 1), 256, 0, stream>>>(
          xhi, xlo, wbuf, nullptr, syn_b + (size_t)l * Nm, scales + 1 + l,
          1, nullptr, hhi, hlo, 1024, 4096, 1024);
      hipMemsetAsync(ob, 0, (size_t)1024 * 1024 * 4, stream);
      tern_kernel<<<2048, 256, 0, stream>>>(out_w + (size_t)l * Dm * Nm, scales + 5 + l,
                                            wbuf, (long)Dm * Nm / 4);
      gemm_kernel<false, false, 64><<<dim3(1024/64, 1024/64, 2), 256, 0, stream>>>(
          hhi, hlo, wbuf, nullptr, out_b + (size_t)l * Dm, scales + 5 + l,
          0, ob, nullptr, nullptr, 1024, 1024, 4096);
    } else {
      gemm_kernel<false, true, 64><<<dim3(4096/64, 1024/64, 1), 256, 0, stream>>>(
          xhi, xlo, syn_w + (size_t)l * Nm * Dm, nullptr, syn_b + (size_t)l * Nm, scales + 1 + l,
          1, nullptr, hhi, hlo, 1024, 4096, 1024);
      hipMemsetAsync(ob, 0, (size_t)1024 * 1024 * 4, stream);
      gemm_kernel<false, true, 64><<<dim3(1024/64, 1024/64, 2), 256, 0, stream>>>(
          hhi, hlo, out_w + (size_t)l * Dm * Nm, nullptr, out_b + (size_t)l * Dm, scales + 5 + l,
          0, ob, nullptr, nullptr, 1024, 1024, 4096);
    }
    // x = LN(resid + out) -> hs f32 + xhi/xlo planes
    // tier1: extra 256 blocks zero the NEXT layer's accumulator (ping-pong)
    float* zb = (tier1 && l < Lm - 1) ? ob_next : nullptr;
    ln_kernel<<<zb ? 1280 : 1024, 256, 0, stream>>>(
        hs, ob, ln_g + (size_t)l * Dm, ln_b + (size_t)l * Dm, hs, xhi, xlo, zb);
  }
  // final LN -> planes only
  ln_kernel<<<1024, 256, 0, stream>>>(hs, nullptr, on_g, on_b, nullptr, xhi, xlo, nullptr);

  // logits = x @ tern(head_w)^T + head_b  (f32 -> d_out)
  if (pre_head){
    // head weights already prepped into wbuf during the GRU shadow
    gemm_lds_kernel<<<2048, 256, 0, stream>>>(
        xhi, xlo, wbuf, head_b, scales + 9, 0, logits, 1024, 32000, 1024);
  } else {
    gemm_kernel<false, true, 128><<<dim3(32000/128, 1024/128, 1), 256, 0, stream>>>(
        xhi, xlo, head_w, nullptr, head_b, scales + 9, 0, logits, nullptr, nullptr, 1024, 32000, 1024);
  }
}